// Round 11
// baseline (306.365 us; speedup 1.0000x reference)
//
#include <hip/hip_runtime.h>

#define N_NODES 80000
#define N_EDGES 1280000
#define F_IN 64
#define F_HID 128
#define F_OUT 40
#define NQ (N_NODES / 4)   // 20000 int4 groups
#define SHP 132            // padded sH stride: 16B-aligned float4 rows

__device__ __forceinline__ unsigned short bf16rn(float f) {
  unsigned u = __float_as_uint(f);
  u += 0x7fffu + ((u >> 16) & 1u);   // round-to-nearest-even
  return (unsigned short)(u >> 16);
}
__device__ __forceinline__ float bflo(unsigned w) { return __uint_as_float(w << 16); }
__device__ __forceinline__ float bfhi(unsigned w) { return __uint_as_float(w & 0xffff0000u); }

// ---------------- x -> bf16 conversion ----------------
__global__ __launch_bounds__(256) void xcvt_kernel(const float4* __restrict__ x4,
                                                   ushort4* __restrict__ xb4) {
  int i = blockIdx.x * 256 + threadIdx.x;
  if (i < N_NODES * F_IN / 4) {
    float4 v = x4[i];
    ushort4 o;
    o.x = bf16rn(v.x); o.y = bf16rn(v.y); o.z = bf16rn(v.z); o.w = bf16rn(v.w);
    xb4[i] = o;
  }
}

// ---------------- CSR build: histogram ----------------
__global__ __launch_bounds__(256) void hist_kernel(const int* __restrict__ src,
                                                   int* __restrict__ deg) {
  int i = blockIdx.x * 256 + threadIdx.x;
  if (i < N_EDGES) atomicAdd(&deg[src[i]], 1);
}

// ------- scan A: 20 blocks, block-local exclusive scan + block sums -------
__global__ __launch_bounds__(1024) void scanA_kernel(const int4* __restrict__ deg4,
                                                     int4* __restrict__ rs4,
                                                     int* __restrict__ bsum) {
  __shared__ int wsum[16];
  __shared__ int woff[16];
  int tid = threadIdx.x, lane = tid & 63, wid = tid >> 6;
  int i = blockIdx.x * 1024 + tid;
  int4 v = (i < NQ) ? deg4[i] : make_int4(0, 0, 0, 0);
  int tot = v.x + v.y + v.z + v.w;
  int s = tot;
#pragma unroll
  for (int off = 1; off < 64; off <<= 1) {
    int t = __shfl_up(s, off, 64);
    if (lane >= off) s += t;
  }
  if (lane == 63) wsum[wid] = s;
  __syncthreads();
  if (wid == 0) {
    int wv = (lane < 16) ? wsum[lane] : 0;
    int ss = wv;
#pragma unroll
    for (int off = 1; off < 16; off <<= 1) {
      int t = __shfl_up(ss, off, 64);
      if (lane >= off) ss += t;
    }
    if (lane < 16) woff[lane] = ss - wv;
    if (lane == 15) bsum[blockIdx.x] = ss;
  }
  __syncthreads();
  int excl = woff[wid] + (s - tot);
  if (i < NQ) {
    int e0 = excl, e1 = e0 + v.x, e2 = e1 + v.y, e3 = e2 + v.z;
    rs4[i] = make_int4(e0, e1, e2, e3);
  }
}

// --- scan C (merged with B): each block reduces the 20 block sums itself ---
__global__ __launch_bounds__(1024) void scanC_kernel(int4* __restrict__ rs4,
                                                     int4* __restrict__ cur4,
                                                     const int* __restrict__ bsum,
                                                     int* __restrict__ rs) {
  __shared__ int s_off;
  int tid = threadIdx.x;
  if (tid < 64) {
    int v = (tid < 20) ? bsum[tid] : 0;
    int p = (tid < (int)blockIdx.x) ? v : 0;
#pragma unroll
    for (int m = 1; m < 64; m <<= 1) {
      p += __shfl_xor(p, m, 64);
      v += __shfl_xor(v, m, 64);
    }
    if (tid == 0) {
      s_off = p;
      if (blockIdx.x == 19) rs[N_NODES] = v;   // grand total
    }
  }
  __syncthreads();
  int o = s_off;
  int i = blockIdx.x * 1024 + tid;
  if (i < NQ) {
    int4 r = rs4[i];
    r.x += o; r.y += o; r.z += o; r.w += o;
    rs4[i] = r;
    cur4[i] = r;
  }
}

// ---------------- CSR build: scatter packed (dst,val) ----------------
__global__ __launch_bounds__(256) void scatter_kernel(
    const int* __restrict__ src, const int* __restrict__ dst,
    const float* __restrict__ vals, int* __restrict__ cur,
    int2* __restrict__ epack) {
  int i = blockIdx.x * 256 + threadIdx.x;
  if (i < N_EDGES) {
    int p = atomicAdd(&cur[src[i]], 1);
    epack[p] = make_int2(dst[i], __float_as_int(vals[i]));
  }
}

// ---- Fused: rows = gather(A, xb) in LDS, then g = relu(rows@W1)@W2 (bf16 out)
// 512 threads = 8 waves; 32 rows/block; wave gathers 4 rows.
// Gather lanes: fi = lane&7 (uint4 = 8 bf16 feats), h = lane>>3 (8 edges/step).
__global__ __launch_bounds__(512, 6) void spmm_dense_kernel(
    const int* __restrict__ rs, const int2* __restrict__ epack,
    const uint4* __restrict__ xb, const float* __restrict__ W1,
    const float* __restrict__ W2, unsigned short* __restrict__ gb) {
  __shared__ float sX[32 * F_IN];     // 8 KB
  __shared__ float sH[32 * SHP];      // 16.5 KB (padded)
  int tid = threadIdx.x, lane = tid & 63, wid = tid >> 6;
  int rbase = blockIdx.x * 32;
  int h = lane >> 3;     // 0..7: which of 8 parallel edges
  int fi = lane & 7;     // feature-oct index (feats 8fi..8fi+7)

#pragma unroll
  for (int r = 0; r < 4; ++r) {
    int node = rbase + wid * 4 + r;
    int j0 = rs[node], j1 = rs[node + 1];
    float a0 = 0.f, a1 = 0.f, a2 = 0.f, a3 = 0.f;
    float a4 = 0.f, a5 = 0.f, a6 = 0.f, a7 = 0.f;
    int j = j0;
    for (; j + 16 <= j1; j += 16) {   // 16 edges in flight
      int2 e0 = epack[j + h];
      int2 e1 = epack[j + 8 + h];
      uint4 q0 = xb[(size_t)e0.x * 8 + fi];
      uint4 q1 = xb[(size_t)e1.x * 8 + fi];
      float v0 = __int_as_float(e0.y), v1 = __int_as_float(e1.y);
      a0 += v0 * bflo(q0.x); a1 += v0 * bfhi(q0.x);
      a2 += v0 * bflo(q0.y); a3 += v0 * bfhi(q0.y);
      a4 += v0 * bflo(q0.z); a5 += v0 * bfhi(q0.z);
      a6 += v0 * bflo(q0.w); a7 += v0 * bfhi(q0.w);
      a0 += v1 * bflo(q1.x); a1 += v1 * bfhi(q1.x);
      a2 += v1 * bflo(q1.y); a3 += v1 * bfhi(q1.y);
      a4 += v1 * bflo(q1.z); a5 += v1 * bfhi(q1.z);
      a6 += v1 * bflo(q1.w); a7 += v1 * bfhi(q1.w);
    }
    for (; j + 8 <= j1; j += 8) {
      int2 e = epack[j + h];
      uint4 q = xb[(size_t)e.x * 8 + fi];
      float v = __int_as_float(e.y);
      a0 += v * bflo(q.x); a1 += v * bfhi(q.x);
      a2 += v * bflo(q.y); a3 += v * bfhi(q.y);
      a4 += v * bflo(q.z); a5 += v * bfhi(q.z);
      a6 += v * bflo(q.w); a7 += v * bfhi(q.w);
    }
    if (h < j1 - j) {                 // tail 0..7 edges
      int2 e = epack[j + h];
      uint4 q = xb[(size_t)e.x * 8 + fi];
      float v = __int_as_float(e.y);
      a0 += v * bflo(q.x); a1 += v * bfhi(q.x);
      a2 += v * bflo(q.y); a3 += v * bfhi(q.y);
      a4 += v * bflo(q.z); a5 += v * bfhi(q.z);
      a6 += v * bflo(q.w); a7 += v * bfhi(q.w);
    }
    // reduce over 8 edge-groups: xor 8, 16, 32
#pragma unroll
    for (int m = 8; m <= 32; m <<= 1) {
      a0 += __shfl_xor(a0, m, 64); a1 += __shfl_xor(a1, m, 64);
      a2 += __shfl_xor(a2, m, 64); a3 += __shfl_xor(a3, m, 64);
      a4 += __shfl_xor(a4, m, 64); a5 += __shfl_xor(a5, m, 64);
      a6 += __shfl_xor(a6, m, 64); a7 += __shfl_xor(a7, m, 64);
    }
    if (lane < 8) {
      float4 o0; o0.x = a0; o0.y = a1; o0.z = a2; o0.w = a3;
      float4 o1; o1.x = a4; o1.y = a5; o1.z = a6; o1.w = a7;
      *(float4*)&sX[(wid * 4 + r) * F_IN + fi * 8] = o0;
      *(float4*)&sX[(wid * 4 + r) * F_IN + fi * 8 + 4] = o1;
    }
  }
  __syncthreads();

  // phase 1: sH = relu(sX @ W1). Per-thread tile 2 rows x 4 cols, k-step 4:
  // 2 ds_read_b128 + 4 coalesced float4 W1 loads per 32 FMAs.
  {
    int cg = tid & 31;         // cols 4cg..4cg+3
    int rg = tid >> 5;         // rows 2rg, 2rg+1
    float4 acc0 = make_float4(0.f, 0.f, 0.f, 0.f);
    float4 acc1 = make_float4(0.f, 0.f, 0.f, 0.f);
    const float4* sX4 = (const float4*)sX;
    for (int k = 0; k < F_IN; k += 4) {
      float4 xa = sX4[((2 * rg) * F_IN + k) >> 2];
      float4 xc = sX4[((2 * rg + 1) * F_IN + k) >> 2];
      float4 w0 = *(const float4*)&W1[(k + 0) * F_HID + cg * 4];
      float4 w1 = *(const float4*)&W1[(k + 1) * F_HID + cg * 4];
      float4 w2 = *(const float4*)&W1[(k + 2) * F_HID + cg * 4];
      float4 w3 = *(const float4*)&W1[(k + 3) * F_HID + cg * 4];
      acc0.x += xa.x * w0.x + xa.y * w1.x + xa.z * w2.x + xa.w * w3.x;
      acc0.y += xa.x * w0.y + xa.y * w1.y + xa.z * w2.y + xa.w * w3.y;
      acc0.z += xa.x * w0.z + xa.y * w1.z + xa.z * w2.z + xa.w * w3.z;
      acc0.w += xa.x * w0.w + xa.y * w1.w + xa.z * w2.w + xa.w * w3.w;
      acc1.x += xc.x * w0.x + xc.y * w1.x + xc.z * w2.x + xc.w * w3.x;
      acc1.y += xc.x * w0.y + xc.y * w1.y + xc.z * w2.y + xc.w * w3.y;
      acc1.z += xc.x * w0.z + xc.y * w1.z + xc.z * w2.z + xc.w * w3.z;
      acc1.w += xc.x * w0.w + xc.y * w1.w + xc.z * w2.w + xc.w * w3.w;
    }
    float4 r0, r1;
    r0.x = fmaxf(acc0.x, 0.f); r0.y = fmaxf(acc0.y, 0.f);
    r0.z = fmaxf(acc0.z, 0.f); r0.w = fmaxf(acc0.w, 0.f);
    r1.x = fmaxf(acc1.x, 0.f); r1.y = fmaxf(acc1.y, 0.f);
    r1.z = fmaxf(acc1.z, 0.f); r1.w = fmaxf(acc1.w, 0.f);
    *(float4*)&sH[(2 * rg) * SHP + cg * 4] = r0;
    *(float4*)&sH[(2 * rg + 1) * SHP + cg * 4] = r1;
  }
  __syncthreads();

  // phase 2: gb = bf16(sH @ W2). 320 active threads: thread = (row, colquad).
  if (tid < 320) {
    int r = tid / 10;          // 0..31
    int cg = tid - r * 10;     // 0..9 -> cols 4cg..4cg+3
    float4 acc = make_float4(0.f, 0.f, 0.f, 0.f);
    for (int k = 0; k < F_HID; k += 4) {
      float4 hq = *(const float4*)&sH[r * SHP + k];
      float4 w0 = *(const float4*)&W2[(k + 0) * F_OUT + cg * 4];
      float4 w1 = *(const float4*)&W2[(k + 1) * F_OUT + cg * 4];
      float4 w2 = *(const float4*)&W2[(k + 2) * F_OUT + cg * 4];
      float4 w3 = *(const float4*)&W2[(k + 3) * F_OUT + cg * 4];
      acc.x += hq.x * w0.x + hq.y * w1.x + hq.z * w2.x + hq.w * w3.x;
      acc.y += hq.x * w0.y + hq.y * w1.y + hq.z * w2.y + hq.w * w3.y;
      acc.z += hq.x * w0.z + hq.y * w1.z + hq.z * w2.z + hq.w * w3.z;
      acc.w += hq.x * w0.w + hq.y * w1.w + hq.z * w2.w + hq.w * w3.w;
    }
    ushort4 ob;
    ob.x = bf16rn(acc.x); ob.y = bf16rn(acc.y);
    ob.z = bf16rn(acc.z); ob.w = bf16rn(acc.w);
    *(ushort4*)&gb[(size_t)(rbase + r) * F_OUT + cg * 4] = ob;
  }
}

// ------- SPMM2 gather: out = A @ gb (40 bf16 feats = 5 lanes x uint4) -------
// 12 edge-groups (60 lanes), 12 edges/step, unroll x2 = 24 in flight.
__global__ __launch_bounds__(256) void spmm2_kernel(
    const int* __restrict__ rs, const int2* __restrict__ epack,
    const uint4* __restrict__ gb4, float* __restrict__ out) {
  int node = (blockIdx.x * 256 + threadIdx.x) >> 6;
  int lane = threadIdx.x & 63;
  if (node >= N_NODES) return;
  int grp = lane / 5;         // 0..11 live, 12 = idle (lanes 60-63)
  int fi = lane % 5;          // feature oct (feats 8fi..8fi+7)
  bool active = grp < 12;
  int j0 = rs[node], j1 = rs[node + 1];
  float a0 = 0.f, a1 = 0.f, a2 = 0.f, a3 = 0.f;
  float a4 = 0.f, a5 = 0.f, a6 = 0.f, a7 = 0.f;
  int j = j0;
  for (; j + 24 <= j1; j += 24) {   // 24 edges in flight
    if (active) {
      int2 e0 = epack[j + grp];
      int2 e1 = epack[j + 12 + grp];
      uint4 q0 = gb4[(size_t)e0.x * 5 + fi];
      uint4 q1 = gb4[(size_t)e1.x * 5 + fi];
      float v0 = __int_as_float(e0.y), v1 = __int_as_float(e1.y);
      a0 += v0 * bflo(q0.x); a1 += v0 * bfhi(q0.x);
      a2 += v0 * bflo(q0.y); a3 += v0 * bfhi(q0.y);
      a4 += v0 * bflo(q0.z); a5 += v0 * bfhi(q0.z);
      a6 += v0 * bflo(q0.w); a7 += v0 * bfhi(q0.w);
      a0 += v1 * bflo(q1.x); a1 += v1 * bfhi(q1.x);
      a2 += v1 * bflo(q1.y); a3 += v1 * bfhi(q1.y);
      a4 += v1 * bflo(q1.z); a5 += v1 * bfhi(q1.z);
      a6 += v1 * bflo(q1.w); a7 += v1 * bfhi(q1.w);
    }
  }
  for (; j + 12 <= j1; j += 12) {
    if (active) {
      int2 e = epack[j + grp];
      uint4 q = gb4[(size_t)e.x * 5 + fi];
      float v = __int_as_float(e.y);
      a0 += v * bflo(q.x); a1 += v * bfhi(q.x);
      a2 += v * bflo(q.y); a3 += v * bfhi(q.y);
      a4 += v * bflo(q.z); a5 += v * bfhi(q.z);
      a6 += v * bflo(q.w); a7 += v * bfhi(q.w);
    }
  }
  if (active && grp < j1 - j) {     // tail 0..11 edges
    int2 e = epack[j + grp];
    uint4 q = gb4[(size_t)e.x * 5 + fi];
    float v = __int_as_float(e.y);
    a0 += v * bflo(q.x); a1 += v * bfhi(q.x);
    a2 += v * bflo(q.y); a3 += v * bfhi(q.y);
    a4 += v * bflo(q.z); a5 += v * bfhi(q.z);
    a6 += v * bflo(q.w); a7 += v * bfhi(q.w);
  }
  // merge 12 groups of 5 lanes: +30, +15, then +5 and +10
  float t0, t1, t2, t3, t4, t5, t6, t7;
  t0 = __shfl(a0, lane + 30, 64); t1 = __shfl(a1, lane + 30, 64);
  t2 = __shfl(a2, lane + 30, 64); t3 = __shfl(a3, lane + 30, 64);
  t4 = __shfl(a4, lane + 30, 64); t5 = __shfl(a5, lane + 30, 64);
  t6 = __shfl(a6, lane + 30, 64); t7 = __shfl(a7, lane + 30, 64);
  if (lane < 30) { a0 += t0; a1 += t1; a2 += t2; a3 += t3;
                   a4 += t4; a5 += t5; a6 += t6; a7 += t7; }
  t0 = __shfl(a0, lane + 15, 64); t1 = __shfl(a1, lane + 15, 64);
  t2 = __shfl(a2, lane + 15, 64); t3 = __shfl(a3, lane + 15, 64);
  t4 = __shfl(a4, lane + 15, 64); t5 = __shfl(a5, lane + 15, 64);
  t6 = __shfl(a6, lane + 15, 64); t7 = __shfl(a7, lane + 15, 64);
  if (lane < 15) { a0 += t0; a1 += t1; a2 += t2; a3 += t3;
                   a4 += t4; a5 += t5; a6 += t6; a7 += t7; }
  float u0, u1, u2, u3, u4, u5, u6, u7;
  t0 = __shfl(a0, lane + 5, 64);  t1 = __shfl(a1, lane + 5, 64);
  t2 = __shfl(a2, lane + 5, 64);  t3 = __shfl(a3, lane + 5, 64);
  t4 = __shfl(a4, lane + 5, 64);  t5 = __shfl(a5, lane + 5, 64);
  t6 = __shfl(a6, lane + 5, 64);  t7 = __shfl(a7, lane + 5, 64);
  u0 = __shfl(a0, lane + 10, 64); u1 = __shfl(a1, lane + 10, 64);
  u2 = __shfl(a2, lane + 10, 64); u3 = __shfl(a3, lane + 10, 64);
  u4 = __shfl(a4, lane + 10, 64); u5 = __shfl(a5, lane + 10, 64);
  u6 = __shfl(a6, lane + 10, 64); u7 = __shfl(a7, lane + 10, 64);
  if (lane < 5) {
    a0 += t0 + u0; a1 += t1 + u1; a2 += t2 + u2; a3 += t3 + u3;
    a4 += t4 + u4; a5 += t5 + u5; a6 += t6 + u6; a7 += t7 + u7;
    float4 o0; o0.x = a0; o0.y = a1; o0.z = a2; o0.w = a3;
    float4 o1; o1.x = a4; o1.y = a5; o1.z = a6; o1.w = a7;
    *(float4*)&out[(size_t)node * F_OUT + fi * 8] = o0;
    *(float4*)&out[(size_t)node * F_OUT + fi * 8 + 4] = o1;
  }
}

extern "C" void kernel_launch(void* const* d_in, const int* in_sizes, int n_in,
                              void* d_out, int out_size, void* d_ws, size_t ws_size,
                              hipStream_t stream) {
  const int* src = (const int*)d_in[0];
  const int* dst = (const int*)d_in[1];
  const float* vals = (const float*)d_in[2];
  const float* x = (const float*)d_in[3];
  const float* W1 = (const float*)d_in[4];
  const float* W2 = (const float*)d_in[5];
  float* out = (float*)d_out;

  // 16B-aligned workspace layout
  int* deg = (int*)d_ws;                           // 80000 ints
  int* rs = deg + 80000;                           // 80001 used, pad to 80004
  int* cur = rs + 80004;                           // 80000
  int2* epack = (int2*)(cur + 80000);              // byte off 960016 (16B-aligned)
  unsigned short* xb = (unsigned short*)(epack + N_EDGES);   // 5.12M bf16 = 10.24 MB
  unsigned short* gb = xb + (size_t)N_NODES * F_IN;          // 3.2M bf16 = 6.4 MB
  int* bsum = (int*)(gb + (size_t)N_NODES * F_OUT);          // 20

  hipMemsetAsync(deg, 0, N_NODES * sizeof(int), stream);

  xcvt_kernel<<<(N_NODES * F_IN / 4 + 255) / 256, 256, 0, stream>>>(
      (const float4*)x, (ushort4*)xb);
  hist_kernel<<<(N_EDGES + 255) / 256, 256, 0, stream>>>(src, deg);
  scanA_kernel<<<20, 1024, 0, stream>>>((const int4*)deg, (int4*)rs, bsum);
  scanC_kernel<<<20, 1024, 0, stream>>>((int4*)rs, (int4*)cur, bsum, rs);
  scatter_kernel<<<(N_EDGES + 255) / 256, 256, 0, stream>>>(src, dst, vals, cur, epack);
  spmm_dense_kernel<<<N_NODES / 32, 512, 0, stream>>>(
      rs, epack, (const uint4*)xb, W1, W2, gb);
  spmm2_kernel<<<(N_NODES * 64 + 255) / 256, 256, 0, stream>>>(
      rs, epack, (const uint4*)gb, out);
}

// Round 12
// 297.127 us; speedup vs baseline: 1.0311x; 1.0311x over previous
//
#include <hip/hip_runtime.h>

#define N_NODES 80000
#define N_EDGES 1280000
#define F_IN 64
#define F_HID 128
#define F_OUT 40
#define NQ (N_NODES / 4)   // 20000 int4 groups
#define SHP 132            // padded sH stride: 16B-aligned float4 rows

__device__ __forceinline__ unsigned short bf16rn(float f) {
  unsigned u = __float_as_uint(f);
  u += 0x7fffu + ((u >> 16) & 1u);   // round-to-nearest-even
  return (unsigned short)(u >> 16);
}
__device__ __forceinline__ float bflo(unsigned w) { return __uint_as_float(w << 16); }
__device__ __forceinline__ float bfhi(unsigned w) { return __uint_as_float(w & 0xffff0000u); }

// ---------------- x -> bf16 conversion ----------------
__global__ __launch_bounds__(256) void xcvt_kernel(const float4* __restrict__ x4,
                                                   ushort4* __restrict__ xb4) {
  int i = blockIdx.x * 256 + threadIdx.x;
  if (i < N_NODES * F_IN / 4) {
    float4 v = x4[i];
    ushort4 o;
    o.x = bf16rn(v.x); o.y = bf16rn(v.y); o.z = bf16rn(v.z); o.w = bf16rn(v.w);
    xb4[i] = o;
  }
}

// ---------------- CSR build: histogram ----------------
__global__ __launch_bounds__(256) void hist_kernel(const int* __restrict__ src,
                                                   int* __restrict__ deg) {
  int i = blockIdx.x * 256 + threadIdx.x;
  if (i < N_EDGES) atomicAdd(&deg[src[i]], 1);
}

// ------- scan A: 20 blocks, block-local exclusive scan + block sums -------
__global__ __launch_bounds__(1024) void scanA_kernel(const int4* __restrict__ deg4,
                                                     int4* __restrict__ rs4,
                                                     int* __restrict__ bsum) {
  __shared__ int wsum[16];
  __shared__ int woff[16];
  int tid = threadIdx.x, lane = tid & 63, wid = tid >> 6;
  int i = blockIdx.x * 1024 + tid;
  int4 v = (i < NQ) ? deg4[i] : make_int4(0, 0, 0, 0);
  int tot = v.x + v.y + v.z + v.w;
  int s = tot;
#pragma unroll
  for (int off = 1; off < 64; off <<= 1) {
    int t = __shfl_up(s, off, 64);
    if (lane >= off) s += t;
  }
  if (lane == 63) wsum[wid] = s;
  __syncthreads();
  if (wid == 0) {
    int wv = (lane < 16) ? wsum[lane] : 0;
    int ss = wv;
#pragma unroll
    for (int off = 1; off < 16; off <<= 1) {
      int t = __shfl_up(ss, off, 64);
      if (lane >= off) ss += t;
    }
    if (lane < 16) woff[lane] = ss - wv;
    if (lane == 15) bsum[blockIdx.x] = ss;
  }
  __syncthreads();
  int excl = woff[wid] + (s - tot);
  if (i < NQ) {
    int e0 = excl, e1 = e0 + v.x, e2 = e1 + v.y, e3 = e2 + v.z;
    rs4[i] = make_int4(e0, e1, e2, e3);
  }
}

// --- scan C (merged with B): each block reduces the 20 block sums itself ---
__global__ __launch_bounds__(1024) void scanC_kernel(int4* __restrict__ rs4,
                                                     int4* __restrict__ cur4,
                                                     const int* __restrict__ bsum,
                                                     int* __restrict__ rs) {
  __shared__ int s_off;
  int tid = threadIdx.x;
  if (tid < 64) {
    int v = (tid < 20) ? bsum[tid] : 0;
    int p = (tid < (int)blockIdx.x) ? v : 0;
#pragma unroll
    for (int m = 1; m < 64; m <<= 1) {
      p += __shfl_xor(p, m, 64);
      v += __shfl_xor(v, m, 64);
    }
    if (tid == 0) {
      s_off = p;
      if (blockIdx.x == 19) rs[N_NODES] = v;   // grand total
    }
  }
  __syncthreads();
  int o = s_off;
  int i = blockIdx.x * 1024 + tid;
  if (i < NQ) {
    int4 r = rs4[i];
    r.x += o; r.y += o; r.z += o; r.w += o;
    rs4[i] = r;
    cur4[i] = r;
  }
}

// ---------------- CSR build: scatter packed (dst,val) ----------------
__global__ __launch_bounds__(256) void scatter_kernel(
    const int* __restrict__ src, const int* __restrict__ dst,
    const float* __restrict__ vals, int* __restrict__ cur,
    int2* __restrict__ epack) {
  int i = blockIdx.x * 256 + threadIdx.x;
  if (i < N_EDGES) {
    int p = atomicAdd(&cur[src[i]], 1);
    epack[p] = make_int2(dst[i], __float_as_int(vals[i]));
  }
}

// ------ gather1: one wave per row, barrier-free: sxgb[node] = bf16(A@xb row) ------
// lanes: fi = lane&7 (uint4 = 8 bf16 feats), h = lane>>3 (8 edges/step).
__global__ __launch_bounds__(256) void gather1_kernel(
    const int* __restrict__ rs, const int2* __restrict__ epack,
    const uint4* __restrict__ xb, uint4* __restrict__ sxgb) {
  int node = (blockIdx.x * 256 + threadIdx.x) >> 6;
  int lane = threadIdx.x & 63;
  if (node >= N_NODES) return;
  int h = lane >> 3;     // 0..7: which of 8 parallel edges
  int fi = lane & 7;     // feature-oct index (feats 8fi..8fi+7)
  int j0 = rs[node], j1 = rs[node + 1];
  float a0 = 0.f, a1 = 0.f, a2 = 0.f, a3 = 0.f;
  float a4 = 0.f, a5 = 0.f, a6 = 0.f, a7 = 0.f;
  int j = j0;
  for (; j + 16 <= j1; j += 16) {   // 16 edges in flight
    int2 e0 = epack[j + h];
    int2 e1 = epack[j + 8 + h];
    uint4 q0 = xb[(size_t)e0.x * 8 + fi];
    uint4 q1 = xb[(size_t)e1.x * 8 + fi];
    float v0 = __int_as_float(e0.y), v1 = __int_as_float(e1.y);
    a0 += v0 * bflo(q0.x); a1 += v0 * bfhi(q0.x);
    a2 += v0 * bflo(q0.y); a3 += v0 * bfhi(q0.y);
    a4 += v0 * bflo(q0.z); a5 += v0 * bfhi(q0.z);
    a6 += v0 * bflo(q0.w); a7 += v0 * bfhi(q0.w);
    a0 += v1 * bflo(q1.x); a1 += v1 * bfhi(q1.x);
    a2 += v1 * bflo(q1.y); a3 += v1 * bfhi(q1.y);
    a4 += v1 * bflo(q1.z); a5 += v1 * bfhi(q1.z);
    a6 += v1 * bflo(q1.w); a7 += v1 * bfhi(q1.w);
  }
  for (; j + 8 <= j1; j += 8) {
    int2 e = epack[j + h];
    uint4 q = xb[(size_t)e.x * 8 + fi];
    float v = __int_as_float(e.y);
    a0 += v * bflo(q.x); a1 += v * bfhi(q.x);
    a2 += v * bflo(q.y); a3 += v * bfhi(q.y);
    a4 += v * bflo(q.z); a5 += v * bfhi(q.z);
    a6 += v * bflo(q.w); a7 += v * bfhi(q.w);
  }
  if (h < j1 - j) {                 // tail 0..7 edges
    int2 e = epack[j + h];
    uint4 q = xb[(size_t)e.x * 8 + fi];
    float v = __int_as_float(e.y);
    a0 += v * bflo(q.x); a1 += v * bfhi(q.x);
    a2 += v * bflo(q.y); a3 += v * bfhi(q.y);
    a4 += v * bflo(q.z); a5 += v * bfhi(q.z);
    a6 += v * bflo(q.w); a7 += v * bfhi(q.w);
  }
  // reduce over 8 edge-groups: xor 8, 16, 32
#pragma unroll
  for (int m = 8; m <= 32; m <<= 1) {
    a0 += __shfl_xor(a0, m, 64); a1 += __shfl_xor(a1, m, 64);
    a2 += __shfl_xor(a2, m, 64); a3 += __shfl_xor(a3, m, 64);
    a4 += __shfl_xor(a4, m, 64); a5 += __shfl_xor(a5, m, 64);
    a6 += __shfl_xor(a6, m, 64); a7 += __shfl_xor(a7, m, 64);
  }
  if (lane < 8) {
    uint4 o;
    o.x = (unsigned)bf16rn(a0) | ((unsigned)bf16rn(a1) << 16);
    o.y = (unsigned)bf16rn(a2) | ((unsigned)bf16rn(a3) << 16);
    o.z = (unsigned)bf16rn(a4) | ((unsigned)bf16rn(a5) << 16);
    o.w = (unsigned)bf16rn(a6) | ((unsigned)bf16rn(a7) << 16);
    sxgb[(size_t)node * 8 + fi] = o;
  }
}

// ---- dense: stage 32 bf16 rows -> f32 LDS, then gb = bf16(relu(sX@W1)@W2) ----
__global__ __launch_bounds__(512, 6) void dense_kernel(
    const uint4* __restrict__ sxgb, const float* __restrict__ W1,
    const float* __restrict__ W2, unsigned short* __restrict__ gb) {
  __shared__ float sX[32 * F_IN];     // 8 KB
  __shared__ float sH[32 * SHP];      // 16.5 KB (padded)
  int tid = threadIdx.x;
  int rbase = blockIdx.x * 32;

  if (tid < 256) {                    // 32 rows x 8 uint4/row, coalesced
    uint4 q = sxgb[blockIdx.x * 256 + tid];
    float4 o0, o1;
    o0.x = bflo(q.x); o0.y = bfhi(q.x); o0.z = bflo(q.y); o0.w = bfhi(q.y);
    o1.x = bflo(q.z); o1.y = bfhi(q.z); o1.z = bflo(q.w); o1.w = bfhi(q.w);
    *(float4*)&sX[tid * 8] = o0;
    *(float4*)&sX[tid * 8 + 4] = o1;
  }
  __syncthreads();

  // phase 1 (round-10 form): 8 rows x 1 col per thread, k-blocked x4,
  // ds_read_b128 broadcasts + coalesced scalar W1 loads.
  {
    int c = tid & 127;
    int r0 = (tid >> 7) * 8;   // 0,8,16,24
    float acc[8];
#pragma unroll
    for (int i = 0; i < 8; ++i) acc[i] = 0.f;
    const float4* sX4 = (const float4*)sX;
    for (int k = 0; k < F_IN; k += 4) {
      float4 xq[8];
#pragma unroll
      for (int i = 0; i < 8; ++i) xq[i] = sX4[((r0 + i) * F_IN + k) >> 2];
      float w0 = W1[(k + 0) * F_HID + c];
      float w1 = W1[(k + 1) * F_HID + c];
      float w2 = W1[(k + 2) * F_HID + c];
      float w3 = W1[(k + 3) * F_HID + c];
#pragma unroll
      for (int i = 0; i < 8; ++i)
        acc[i] += xq[i].x * w0 + xq[i].y * w1 + xq[i].z * w2 + xq[i].w * w3;
    }
#pragma unroll
    for (int i = 0; i < 8; ++i) sH[(r0 + i) * SHP + c] = fmaxf(acc[i], 0.f);
  }
  __syncthreads();

  // phase 2: gb = bf16(sH @ W2). 320 active threads: thread = (row, colquad).
  if (tid < 320) {
    int r = tid / 10;          // 0..31
    int cg = tid - r * 10;     // 0..9 -> cols 4cg..4cg+3
    float4 acc = make_float4(0.f, 0.f, 0.f, 0.f);
    for (int k = 0; k < F_HID; k += 4) {
      float4 hq = *(const float4*)&sH[r * SHP + k];
      float4 w0 = *(const float4*)&W2[(k + 0) * F_OUT + cg * 4];
      float4 w1 = *(const float4*)&W2[(k + 1) * F_OUT + cg * 4];
      float4 w2 = *(const float4*)&W2[(k + 2) * F_OUT + cg * 4];
      float4 w3 = *(const float4*)&W2[(k + 3) * F_OUT + cg * 4];
      acc.x += hq.x * w0.x + hq.y * w1.x + hq.z * w2.x + hq.w * w3.x;
      acc.y += hq.x * w0.y + hq.y * w1.y + hq.z * w2.y + hq.w * w3.y;
      acc.z += hq.x * w0.z + hq.y * w1.z + hq.z * w2.z + hq.w * w3.z;
      acc.w += hq.x * w0.w + hq.y * w1.w + hq.z * w2.w + hq.w * w3.w;
    }
    ushort4 ob;
    ob.x = bf16rn(acc.x); ob.y = bf16rn(acc.y);
    ob.z = bf16rn(acc.z); ob.w = bf16rn(acc.w);
    *(ushort4*)&gb[(size_t)(rbase + r) * F_OUT + cg * 4] = ob;
  }
}

// ------- SPMM2 gather: out = A @ gb (40 bf16 feats = 5 lanes x uint4) -------
// 12 edge-groups (60 lanes), 12 edges/step, unroll x2 = 24 in flight.
__global__ __launch_bounds__(256) void spmm2_kernel(
    const int* __restrict__ rs, const int2* __restrict__ epack,
    const uint4* __restrict__ gb4, float* __restrict__ out) {
  int node = (blockIdx.x * 256 + threadIdx.x) >> 6;
  int lane = threadIdx.x & 63;
  if (node >= N_NODES) return;
  int grp = lane / 5;         // 0..11 live, 12 = idle (lanes 60-63)
  int fi = lane % 5;          // feature oct (feats 8fi..8fi+7)
  bool active = grp < 12;
  int j0 = rs[node], j1 = rs[node + 1];
  float a0 = 0.f, a1 = 0.f, a2 = 0.f, a3 = 0.f;
  float a4 = 0.f, a5 = 0.f, a6 = 0.f, a7 = 0.f;
  int j = j0;
  for (; j + 24 <= j1; j += 24) {   // 24 edges in flight
    if (active) {
      int2 e0 = epack[j + grp];
      int2 e1 = epack[j + 12 + grp];
      uint4 q0 = gb4[(size_t)e0.x * 5 + fi];
      uint4 q1 = gb4[(size_t)e1.x * 5 + fi];
      float v0 = __int_as_float(e0.y), v1 = __int_as_float(e1.y);
      a0 += v0 * bflo(q0.x); a1 += v0 * bfhi(q0.x);
      a2 += v0 * bflo(q0.y); a3 += v0 * bfhi(q0.y);
      a4 += v0 * bflo(q0.z); a5 += v0 * bfhi(q0.z);
      a6 += v0 * bflo(q0.w); a7 += v0 * bfhi(q0.w);
      a0 += v1 * bflo(q1.x); a1 += v1 * bfhi(q1.x);
      a2 += v1 * bflo(q1.y); a3 += v1 * bfhi(q1.y);
      a4 += v1 * bflo(q1.z); a5 += v1 * bfhi(q1.z);
      a6 += v1 * bflo(q1.w); a7 += v1 * bfhi(q1.w);
    }
  }
  for (; j + 12 <= j1; j += 12) {
    if (active) {
      int2 e = epack[j + grp];
      uint4 q = gb4[(size_t)e.x * 5 + fi];
      float v = __int_as_float(e.y);
      a0 += v * bflo(q.x); a1 += v * bfhi(q.x);
      a2 += v * bflo(q.y); a3 += v * bfhi(q.y);
      a4 += v * bflo(q.z); a5 += v * bfhi(q.z);
      a6 += v * bflo(q.w); a7 += v * bfhi(q.w);
    }
  }
  if (active && grp < j1 - j) {     // tail 0..11 edges
    int2 e = epack[j + grp];
    uint4 q = gb4[(size_t)e.x * 5 + fi];
    float v = __int_as_float(e.y);
    a0 += v * bflo(q.x); a1 += v * bfhi(q.x);
    a2 += v * bflo(q.y); a3 += v * bfhi(q.y);
    a4 += v * bflo(q.z); a5 += v * bfhi(q.z);
    a6 += v * bflo(q.w); a7 += v * bfhi(q.w);
  }
  // merge 12 groups of 5 lanes: +30, +15, then +5 and +10
  float t0, t1, t2, t3, t4, t5, t6, t7;
  t0 = __shfl(a0, lane + 30, 64); t1 = __shfl(a1, lane + 30, 64);
  t2 = __shfl(a2, lane + 30, 64); t3 = __shfl(a3, lane + 30, 64);
  t4 = __shfl(a4, lane + 30, 64); t5 = __shfl(a5, lane + 30, 64);
  t6 = __shfl(a6, lane + 30, 64); t7 = __shfl(a7, lane + 30, 64);
  if (lane < 30) { a0 += t0; a1 += t1; a2 += t2; a3 += t3;
                   a4 += t4; a5 += t5; a6 += t6; a7 += t7; }
  t0 = __shfl(a0, lane + 15, 64); t1 = __shfl(a1, lane + 15, 64);
  t2 = __shfl(a2, lane + 15, 64); t3 = __shfl(a3, lane + 15, 64);
  t4 = __shfl(a4, lane + 15, 64); t5 = __shfl(a5, lane + 15, 64);
  t6 = __shfl(a6, lane + 15, 64); t7 = __shfl(a7, lane + 15, 64);
  if (lane < 15) { a0 += t0; a1 += t1; a2 += t2; a3 += t3;
                   a4 += t4; a5 += t5; a6 += t6; a7 += t7; }
  float u0, u1, u2, u3, u4, u5, u6, u7;
  t0 = __shfl(a0, lane + 5, 64);  t1 = __shfl(a1, lane + 5, 64);
  t2 = __shfl(a2, lane + 5, 64);  t3 = __shfl(a3, lane + 5, 64);
  t4 = __shfl(a4, lane + 5, 64);  t5 = __shfl(a5, lane + 5, 64);
  t6 = __shfl(a6, lane + 5, 64);  t7 = __shfl(a7, lane + 5, 64);
  u0 = __shfl(a0, lane + 10, 64); u1 = __shfl(a1, lane + 10, 64);
  u2 = __shfl(a2, lane + 10, 64); u3 = __shfl(a3, lane + 10, 64);
  u4 = __shfl(a4, lane + 10, 64); u5 = __shfl(a5, lane + 10, 64);
  u6 = __shfl(a6, lane + 10, 64); u7 = __shfl(a7, lane + 10, 64);
  if (lane < 5) {
    a0 += t0 + u0; a1 += t1 + u1; a2 += t2 + u2; a3 += t3 + u3;
    a4 += t4 + u4; a5 += t5 + u5; a6 += t6 + u6; a7 += t7 + u7;
    float4 o0; o0.x = a0; o0.y = a1; o0.z = a2; o0.w = a3;
    float4 o1; o1.x = a4; o1.y = a5; o1.z = a6; o1.w = a7;
    *(float4*)&out[(size_t)node * F_OUT + fi * 8] = o0;
    *(float4*)&out[(size_t)node * F_OUT + fi * 8 + 4] = o1;
  }
}

extern "C" void kernel_launch(void* const* d_in, const int* in_sizes, int n_in,
                              void* d_out, int out_size, void* d_ws, size_t ws_size,
                              hipStream_t stream) {
  const int* src = (const int*)d_in[0];
  const int* dst = (const int*)d_in[1];
  const float* vals = (const float*)d_in[2];
  const float* x = (const float*)d_in[3];
  const float* W1 = (const float*)d_in[4];
  const float* W2 = (const float*)d_in[5];
  float* out = (float*)d_out;

  // 16B-aligned workspace layout (~38.1 MB)
  int* deg = (int*)d_ws;                           // 80000 ints
  int* rs = deg + 80000;                           // 80001 used, pad to 80004
  int* cur = rs + 80004;                           // 80000
  int2* epack = (int2*)(cur + 80000);              // byte off 960016 (16B-aligned)
  unsigned short* xb = (unsigned short*)(epack + N_EDGES);   // 5.12M bf16 = 10.24 MB
  unsigned short* gb = xb + (size_t)N_NODES * F_IN;          // 3.2M bf16 = 6.4 MB
  unsigned short* sxgb = gb + (size_t)N_NODES * F_OUT;       // 5.12M bf16 = 10.24 MB
  int* bsum = (int*)(sxgb + (size_t)N_NODES * F_IN);         // 20

  hipMemsetAsync(deg, 0, N_NODES * sizeof(int), stream);

  xcvt_kernel<<<(N_NODES * F_IN / 4 + 255) / 256, 256, 0, stream>>>(
      (const float4*)x, (ushort4*)xb);
  hist_kernel<<<(N_EDGES + 255) / 256, 256, 0, stream>>>(src, deg);
  scanA_kernel<<<20, 1024, 0, stream>>>((const int4*)deg, (int4*)rs, bsum);
  scanC_kernel<<<20, 1024, 0, stream>>>((int4*)rs, (int4*)cur, bsum, rs);
  scatter_kernel<<<(N_EDGES + 255) / 256, 256, 0, stream>>>(src, dst, vals, cur, epack);
  gather1_kernel<<<(N_NODES * 64 + 255) / 256, 256, 0, stream>>>(
      rs, epack, (const uint4*)xb, (uint4*)sxgb);
  dense_kernel<<<N_NODES / 32, 512, 0, stream>>>(
      (const uint4*)sxgb, W1, W2, gb);
  spmm2_kernel<<<(N_NODES * 64 + 255) / 256, 256, 0, stream>>>(
      rs, epack, (const uint4*)gb, out);
}

// Round 13
// 284.963 us; speedup vs baseline: 1.0751x; 1.0427x over previous
//
#include <hip/hip_runtime.h>

#define N_NODES 80000
#define N_EDGES 1280000
#define F_IN 64
#define F_HID 128
#define F_OUT 40
#define NQ (N_NODES / 4)   // 20000 int4 groups
#define SHP 132            // padded sH stride: 16B-aligned float4 rows
#define SC_PASSES 8
#define SC_RANGE (N_NODES / SC_PASSES)        // 10000 src values per pass
#define SC_BLOCKS ((N_EDGES + 255) / 256)     // 5000 blocks per pass

__device__ __forceinline__ unsigned short bf16rn(float f) {
  unsigned u = __float_as_uint(f);
  u += 0x7fffu + ((u >> 16) & 1u);   // round-to-nearest-even
  return (unsigned short)(u >> 16);
}
__device__ __forceinline__ float bflo(unsigned w) { return __uint_as_float(w << 16); }
__device__ __forceinline__ float bfhi(unsigned w) { return __uint_as_float(w & 0xffff0000u); }

// ---------------- x -> bf16 conversion ----------------
__global__ __launch_bounds__(256) void xcvt_kernel(const float4* __restrict__ x4,
                                                   ushort4* __restrict__ xb4) {
  int i = blockIdx.x * 256 + threadIdx.x;
  if (i < N_NODES * F_IN / 4) {
    float4 v = x4[i];
    ushort4 o;
    o.x = bf16rn(v.x); o.y = bf16rn(v.y); o.z = bf16rn(v.z); o.w = bf16rn(v.w);
    xb4[i] = o;
  }
}

// ---------------- CSR build: histogram ----------------
__global__ __launch_bounds__(256) void hist_kernel(const int* __restrict__ src,
                                                   int* __restrict__ deg) {
  int i = blockIdx.x * 256 + threadIdx.x;
  if (i < N_EDGES) atomicAdd(&deg[src[i]], 1);
}

// ------- scan A: 20 blocks, block-local exclusive scan + block sums -------
__global__ __launch_bounds__(1024) void scanA_kernel(const int4* __restrict__ deg4,
                                                     int4* __restrict__ rs4,
                                                     int* __restrict__ bsum) {
  __shared__ int wsum[16];
  __shared__ int woff[16];
  int tid = threadIdx.x, lane = tid & 63, wid = tid >> 6;
  int i = blockIdx.x * 1024 + tid;
  int4 v = (i < NQ) ? deg4[i] : make_int4(0, 0, 0, 0);
  int tot = v.x + v.y + v.z + v.w;
  int s = tot;
#pragma unroll
  for (int off = 1; off < 64; off <<= 1) {
    int t = __shfl_up(s, off, 64);
    if (lane >= off) s += t;
  }
  if (lane == 63) wsum[wid] = s;
  __syncthreads();
  if (wid == 0) {
    int wv = (lane < 16) ? wsum[lane] : 0;
    int ss = wv;
#pragma unroll
    for (int off = 1; off < 16; off <<= 1) {
      int t = __shfl_up(ss, off, 64);
      if (lane >= off) ss += t;
    }
    if (lane < 16) woff[lane] = ss - wv;
    if (lane == 15) bsum[blockIdx.x] = ss;
  }
  __syncthreads();
  int excl = woff[wid] + (s - tot);
  if (i < NQ) {
    int e0 = excl, e1 = e0 + v.x, e2 = e1 + v.y, e3 = e2 + v.z;
    rs4[i] = make_int4(e0, e1, e2, e3);
  }
}

// --- scan C (merged with B): each block reduces the 20 block sums itself ---
__global__ __launch_bounds__(1024) void scanC_kernel(int4* __restrict__ rs4,
                                                     int4* __restrict__ cur4,
                                                     const int* __restrict__ bsum,
                                                     int* __restrict__ rs) {
  __shared__ int s_off;
  int tid = threadIdx.x;
  if (tid < 64) {
    int v = (tid < 20) ? bsum[tid] : 0;
    int p = (tid < (int)blockIdx.x) ? v : 0;
#pragma unroll
    for (int m = 1; m < 64; m <<= 1) {
      p += __shfl_xor(p, m, 64);
      v += __shfl_xor(v, m, 64);
    }
    if (tid == 0) {
      s_off = p;
      if (blockIdx.x == 19) rs[N_NODES] = v;   // grand total
    }
  }
  __syncthreads();
  int o = s_off;
  int i = blockIdx.x * 1024 + tid;
  if (i < NQ) {
    int4 r = rs4[i];
    r.x += o; r.y += o; r.z += o; r.w += o;
    rs4[i] = r;
    cur4[i] = r;
  }
}

// ------- CSR build: windowed scatter (8 passes, L2-resident write window) -------
// pass = blockIdx / SC_BLOCKS; only edges with src in the pass's 10000-node
// range are scattered. Blocks dispatch in order -> each pass's writes hit a
// ~1.3 MB CSR window that stays L2-resident (kills write-allocate inflation).
__global__ __launch_bounds__(256) void scatter_kernel(
    const int* __restrict__ src, const int* __restrict__ dst,
    const float* __restrict__ vals, int* __restrict__ cur,
    int2* __restrict__ epack) {
  int pass = blockIdx.x / SC_BLOCKS;
  int i = (blockIdx.x - pass * SC_BLOCKS) * 256 + threadIdx.x;
  if (i >= N_EDGES) return;
  int s = src[i];
  if ((unsigned)(s - pass * SC_RANGE) < (unsigned)SC_RANGE) {
    int p = atomicAdd(&cur[s], 1);
    epack[p] = make_int2(dst[i], __float_as_int(vals[i]));
  }
}

// ------ gather1: one wave per row, barrier-free: sxgb[node] = bf16(A@xb row) ------
// lanes: fi = lane&7 (uint4 = 8 bf16 feats), h = lane>>3 (8 edges/step).
__global__ __launch_bounds__(256) void gather1_kernel(
    const int* __restrict__ rs, const int2* __restrict__ epack,
    const uint4* __restrict__ xb, uint4* __restrict__ sxgb) {
  int node = (blockIdx.x * 256 + threadIdx.x) >> 6;
  int lane = threadIdx.x & 63;
  if (node >= N_NODES) return;
  int h = lane >> 3;     // 0..7: which of 8 parallel edges
  int fi = lane & 7;     // feature-oct index (feats 8fi..8fi+7)
  int j0 = rs[node], j1 = rs[node + 1];
  float a0 = 0.f, a1 = 0.f, a2 = 0.f, a3 = 0.f;
  float a4 = 0.f, a5 = 0.f, a6 = 0.f, a7 = 0.f;
  int j = j0;
  for (; j + 16 <= j1; j += 16) {   // 16 edges in flight
    int2 e0 = epack[j + h];
    int2 e1 = epack[j + 8 + h];
    uint4 q0 = xb[(size_t)e0.x * 8 + fi];
    uint4 q1 = xb[(size_t)e1.x * 8 + fi];
    float v0 = __int_as_float(e0.y), v1 = __int_as_float(e1.y);
    a0 += v0 * bflo(q0.x); a1 += v0 * bfhi(q0.x);
    a2 += v0 * bflo(q0.y); a3 += v0 * bfhi(q0.y);
    a4 += v0 * bflo(q0.z); a5 += v0 * bfhi(q0.z);
    a6 += v0 * bflo(q0.w); a7 += v0 * bfhi(q0.w);
    a0 += v1 * bflo(q1.x); a1 += v1 * bfhi(q1.x);
    a2 += v1 * bflo(q1.y); a3 += v1 * bfhi(q1.y);
    a4 += v1 * bflo(q1.z); a5 += v1 * bfhi(q1.z);
    a6 += v1 * bflo(q1.w); a7 += v1 * bfhi(q1.w);
  }
  for (; j + 8 <= j1; j += 8) {
    int2 e = epack[j + h];
    uint4 q = xb[(size_t)e.x * 8 + fi];
    float v = __int_as_float(e.y);
    a0 += v * bflo(q.x); a1 += v * bfhi(q.x);
    a2 += v * bflo(q.y); a3 += v * bfhi(q.y);
    a4 += v * bflo(q.z); a5 += v * bfhi(q.z);
    a6 += v * bflo(q.w); a7 += v * bfhi(q.w);
  }
  if (h < j1 - j) {                 // tail 0..7 edges
    int2 e = epack[j + h];
    uint4 q = xb[(size_t)e.x * 8 + fi];
    float v = __int_as_float(e.y);
    a0 += v * bflo(q.x); a1 += v * bfhi(q.x);
    a2 += v * bflo(q.y); a3 += v * bfhi(q.y);
    a4 += v * bflo(q.z); a5 += v * bfhi(q.z);
    a6 += v * bflo(q.w); a7 += v * bfhi(q.w);
  }
  // reduce over 8 edge-groups: xor 8, 16, 32
#pragma unroll
  for (int m = 8; m <= 32; m <<= 1) {
    a0 += __shfl_xor(a0, m, 64); a1 += __shfl_xor(a1, m, 64);
    a2 += __shfl_xor(a2, m, 64); a3 += __shfl_xor(a3, m, 64);
    a4 += __shfl_xor(a4, m, 64); a5 += __shfl_xor(a5, m, 64);
    a6 += __shfl_xor(a6, m, 64); a7 += __shfl_xor(a7, m, 64);
  }
  if (lane < 8) {
    uint4 o;
    o.x = (unsigned)bf16rn(a0) | ((unsigned)bf16rn(a1) << 16);
    o.y = (unsigned)bf16rn(a2) | ((unsigned)bf16rn(a3) << 16);
    o.z = (unsigned)bf16rn(a4) | ((unsigned)bf16rn(a5) << 16);
    o.w = (unsigned)bf16rn(a6) | ((unsigned)bf16rn(a7) << 16);
    sxgb[(size_t)node * 8 + fi] = o;
  }
}

// ---- dense: stage 32 bf16 rows -> f32 LDS, then gb = bf16(relu(sX@W1)@W2) ----
__global__ __launch_bounds__(512, 6) void dense_kernel(
    const uint4* __restrict__ sxgb, const float* __restrict__ W1,
    const float* __restrict__ W2, unsigned short* __restrict__ gb) {
  __shared__ float sX[32 * F_IN];     // 8 KB
  __shared__ float sH[32 * SHP];      // 16.5 KB (padded)
  int tid = threadIdx.x;
  int rbase = blockIdx.x * 32;

  if (tid < 256) {                    // 32 rows x 8 uint4/row, coalesced
    uint4 q = sxgb[blockIdx.x * 256 + tid];
    float4 o0, o1;
    o0.x = bflo(q.x); o0.y = bfhi(q.x); o0.z = bflo(q.y); o0.w = bfhi(q.y);
    o1.x = bflo(q.z); o1.y = bfhi(q.z); o1.z = bflo(q.w); o1.w = bfhi(q.w);
    *(float4*)&sX[tid * 8] = o0;
    *(float4*)&sX[tid * 8 + 4] = o1;
  }
  __syncthreads();

  // phase 1: 8 rows x 1 col per thread, k-blocked x4,
  // ds_read_b128 broadcasts + coalesced scalar W1 loads.
  {
    int c = tid & 127;
    int r0 = (tid >> 7) * 8;   // 0,8,16,24
    float acc[8];
#pragma unroll
    for (int i = 0; i < 8; ++i) acc[i] = 0.f;
    const float4* sX4 = (const float4*)sX;
    for (int k = 0; k < F_IN; k += 4) {
      float4 xq[8];
#pragma unroll
      for (int i = 0; i < 8; ++i) xq[i] = sX4[((r0 + i) * F_IN + k) >> 2];
      float w0 = W1[(k + 0) * F_HID + c];
      float w1 = W1[(k + 1) * F_HID + c];
      float w2 = W1[(k + 2) * F_HID + c];
      float w3 = W1[(k + 3) * F_HID + c];
#pragma unroll
      for (int i = 0; i < 8; ++i)
        acc[i] += xq[i].x * w0 + xq[i].y * w1 + xq[i].z * w2 + xq[i].w * w3;
    }
#pragma unroll
    for (int i = 0; i < 8; ++i) sH[(r0 + i) * SHP + c] = fmaxf(acc[i], 0.f);
  }
  __syncthreads();

  // phase 2: gb = bf16(sH @ W2). 320 active threads: thread = (row, colquad).
  if (tid < 320) {
    int r = tid / 10;          // 0..31
    int cg = tid - r * 10;     // 0..9 -> cols 4cg..4cg+3
    float4 acc = make_float4(0.f, 0.f, 0.f, 0.f);
    for (int k = 0; k < F_HID; k += 4) {
      float4 hq = *(const float4*)&sH[r * SHP + k];
      float4 w0 = *(const float4*)&W2[(k + 0) * F_OUT + cg * 4];
      float4 w1 = *(const float4*)&W2[(k + 1) * F_OUT + cg * 4];
      float4 w2 = *(const float4*)&W2[(k + 2) * F_OUT + cg * 4];
      float4 w3 = *(const float4*)&W2[(k + 3) * F_OUT + cg * 4];
      acc.x += hq.x * w0.x + hq.y * w1.x + hq.z * w2.x + hq.w * w3.x;
      acc.y += hq.x * w0.y + hq.y * w1.y + hq.z * w2.y + hq.w * w3.y;
      acc.z += hq.x * w0.z + hq.y * w1.z + hq.z * w2.z + hq.w * w3.z;
      acc.w += hq.x * w0.w + hq.y * w1.w + hq.z * w2.w + hq.w * w3.w;
    }
    ushort4 ob;
    ob.x = bf16rn(acc.x); ob.y = bf16rn(acc.y);
    ob.z = bf16rn(acc.z); ob.w = bf16rn(acc.w);
    *(ushort4*)&gb[(size_t)(rbase + r) * F_OUT + cg * 4] = ob;
  }
}

// ------- SPMM2 gather: out = A @ gb (40 bf16 feats = 5 lanes x uint4) -------
// 12 edge-groups (60 lanes), 12 edges/step, unroll x2 = 24 in flight.
__global__ __launch_bounds__(256) void spmm2_kernel(
    const int* __restrict__ rs, const int2* __restrict__ epack,
    const uint4* __restrict__ gb4, float* __restrict__ out) {
  int node = (blockIdx.x * 256 + threadIdx.x) >> 6;
  int lane = threadIdx.x & 63;
  if (node >= N_NODES) return;
  int grp = lane / 5;         // 0..11 live, 12 = idle (lanes 60-63)
  int fi = lane % 5;          // feature oct (feats 8fi..8fi+7)
  bool active = grp < 12;
  int j0 = rs[node], j1 = rs[node + 1];
  float a0 = 0.f, a1 = 0.f, a2 = 0.f, a3 = 0.f;
  float a4 = 0.f, a5 = 0.f, a6 = 0.f, a7 = 0.f;
  int j = j0;
  for (; j + 24 <= j1; j += 24) {   // 24 edges in flight
    if (active) {
      int2 e0 = epack[j + grp];
      int2 e1 = epack[j + 12 + grp];
      uint4 q0 = gb4[(size_t)e0.x * 5 + fi];
      uint4 q1 = gb4[(size_t)e1.x * 5 + fi];
      float v0 = __int_as_float(e0.y), v1 = __int_as_float(e1.y);
      a0 += v0 * bflo(q0.x); a1 += v0 * bfhi(q0.x);
      a2 += v0 * bflo(q0.y); a3 += v0 * bfhi(q0.y);
      a4 += v0 * bflo(q0.z); a5 += v0 * bfhi(q0.z);
      a6 += v0 * bflo(q0.w); a7 += v0 * bfhi(q0.w);
      a0 += v1 * bflo(q1.x); a1 += v1 * bfhi(q1.x);
      a2 += v1 * bflo(q1.y); a3 += v1 * bfhi(q1.y);
      a4 += v1 * bflo(q1.z); a5 += v1 * bfhi(q1.z);
      a6 += v1 * bflo(q1.w); a7 += v1 * bfhi(q1.w);
    }
  }
  for (; j + 12 <= j1; j += 12) {
    if (active) {
      int2 e = epack[j + grp];
      uint4 q = gb4[(size_t)e.x * 5 + fi];
      float v = __int_as_float(e.y);
      a0 += v * bflo(q.x); a1 += v * bfhi(q.x);
      a2 += v * bflo(q.y); a3 += v * bfhi(q.y);
      a4 += v * bflo(q.z); a5 += v * bfhi(q.z);
      a6 += v * bflo(q.w); a7 += v * bfhi(q.w);
    }
  }
  if (active && grp < j1 - j) {     // tail 0..11 edges
    int2 e = epack[j + grp];
    uint4 q = gb4[(size_t)e.x * 5 + fi];
    float v = __int_as_float(e.y);
    a0 += v * bflo(q.x); a1 += v * bfhi(q.x);
    a2 += v * bflo(q.y); a3 += v * bfhi(q.y);
    a4 += v * bflo(q.z); a5 += v * bfhi(q.z);
    a6 += v * bflo(q.w); a7 += v * bfhi(q.w);
  }
  // merge 12 groups of 5 lanes: +30, +15, then +5 and +10
  float t0, t1, t2, t3, t4, t5, t6, t7;
  t0 = __shfl(a0, lane + 30, 64); t1 = __shfl(a1, lane + 30, 64);
  t2 = __shfl(a2, lane + 30, 64); t3 = __shfl(a3, lane + 30, 64);
  t4 = __shfl(a4, lane + 30, 64); t5 = __shfl(a5, lane + 30, 64);
  t6 = __shfl(a6, lane + 30, 64); t7 = __shfl(a7, lane + 30, 64);
  if (lane < 30) { a0 += t0; a1 += t1; a2 += t2; a3 += t3;
                   a4 += t4; a5 += t5; a6 += t6; a7 += t7; }
  t0 = __shfl(a0, lane + 15, 64); t1 = __shfl(a1, lane + 15, 64);
  t2 = __shfl(a2, lane + 15, 64); t3 = __shfl(a3, lane + 15, 64);
  t4 = __shfl(a4, lane + 15, 64); t5 = __shfl(a5, lane + 15, 64);
  t6 = __shfl(a6, lane + 15, 64); t7 = __shfl(a7, lane + 15, 64);
  if (lane < 15) { a0 += t0; a1 += t1; a2 += t2; a3 += t3;
                   a4 += t4; a5 += t5; a6 += t6; a7 += t7; }
  float u0, u1, u2, u3, u4, u5, u6, u7;
  t0 = __shfl(a0, lane + 5, 64);  t1 = __shfl(a1, lane + 5, 64);
  t2 = __shfl(a2, lane + 5, 64);  t3 = __shfl(a3, lane + 5, 64);
  t4 = __shfl(a4, lane + 5, 64);  t5 = __shfl(a5, lane + 5, 64);
  t6 = __shfl(a6, lane + 5, 64);  t7 = __shfl(a7, lane + 5, 64);
  u0 = __shfl(a0, lane + 10, 64); u1 = __shfl(a1, lane + 10, 64);
  u2 = __shfl(a2, lane + 10, 64); u3 = __shfl(a3, lane + 10, 64);
  u4 = __shfl(a4, lane + 10, 64); u5 = __shfl(a5, lane + 10, 64);
  u6 = __shfl(a6, lane + 10, 64); u7 = __shfl(a7, lane + 10, 64);
  if (lane < 5) {
    a0 += t0 + u0; a1 += t1 + u1; a2 += t2 + u2; a3 += t3 + u3;
    a4 += t4 + u4; a5 += t5 + u5; a6 += t6 + u6; a7 += t7 + u7;
    float4 o0; o0.x = a0; o0.y = a1; o0.z = a2; o0.w = a3;
    float4 o1; o1.x = a4; o1.y = a5; o1.z = a6; o1.w = a7;
    *(float4*)&out[(size_t)node * F_OUT + fi * 8] = o0;
    *(float4*)&out[(size_t)node * F_OUT + fi * 8 + 4] = o1;
  }
}

extern "C" void kernel_launch(void* const* d_in, const int* in_sizes, int n_in,
                              void* d_out, int out_size, void* d_ws, size_t ws_size,
                              hipStream_t stream) {
  const int* src = (const int*)d_in[0];
  const int* dst = (const int*)d_in[1];
  const float* vals = (const float*)d_in[2];
  const float* x = (const float*)d_in[3];
  const float* W1 = (const float*)d_in[4];
  const float* W2 = (const float*)d_in[5];
  float* out = (float*)d_out;

  // 16B-aligned workspace layout (~38.1 MB)
  int* deg = (int*)d_ws;                           // 80000 ints
  int* rs = deg + 80000;                           // 80001 used, pad to 80004
  int* cur = rs + 80004;                           // 80000
  int2* epack = (int2*)(cur + 80000);              // byte off 960016 (16B-aligned)
  unsigned short* xb = (unsigned short*)(epack + N_EDGES);   // 5.12M bf16 = 10.24 MB
  unsigned short* gb = xb + (size_t)N_NODES * F_IN;          // 3.2M bf16 = 6.4 MB
  unsigned short* sxgb = gb + (size_t)N_NODES * F_OUT;       // 5.12M bf16 = 10.24 MB
  int* bsum = (int*)(sxgb + (size_t)N_NODES * F_IN);         // 20

  hipMemsetAsync(deg, 0, N_NODES * sizeof(int), stream);

  xcvt_kernel<<<(N_NODES * F_IN / 4 + 255) / 256, 256, 0, stream>>>(
      (const float4*)x, (ushort4*)xb);
  hist_kernel<<<(N_EDGES + 255) / 256, 256, 0, stream>>>(src, deg);
  scanA_kernel<<<20, 1024, 0, stream>>>((const int4*)deg, (int4*)rs, bsum);
  scanC_kernel<<<20, 1024, 0, stream>>>((int4*)rs, (int4*)cur, bsum, rs);
  scatter_kernel<<<SC_PASSES * SC_BLOCKS, 256, 0, stream>>>(src, dst, vals, cur, epack);
  gather1_kernel<<<(N_NODES * 64 + 255) / 256, 256, 0, stream>>>(
      rs, epack, (const uint4*)xb, (uint4*)sxgb);
  dense_kernel<<<N_NODES / 32, 512, 0, stream>>>(
      (const uint4*)sxgb, W1, W2, gb);
  spmm2_kernel<<<(N_NODES * 64 + 255) / 256, 256, 0, stream>>>(
      rs, epack, (const uint4*)gb, out);
}

// Round 14
// 225.147 us; speedup vs baseline: 1.3607x; 1.2657x over previous
//
#include <hip/hip_runtime.h>

#define N_NODES 80000
#define N_EDGES 1280000
#define F_IN 64
#define F_HID 128
#define F_OUT 40
#define NQ (N_NODES / 4)   // 20000 int4 groups
#define SC_PASSES 8
#define SC_RANGE (N_NODES / SC_PASSES)        // 10000 src values per pass
#define SC_BLOCKS ((N_EDGES + 255) / 256)     // 5000 blocks per pass
#define SAP 72             // sA bf16 stride (row 64 + pad 8)
#define SPP 136            // sP bf16 stride (row 128 + pad 8)

typedef __attribute__((ext_vector_type(8))) short bf16x8;
typedef __attribute__((ext_vector_type(4))) float f32x4;

__device__ __forceinline__ unsigned short bf16rn(float f) {
  unsigned u = __float_as_uint(f);
  u += 0x7fffu + ((u >> 16) & 1u);   // round-to-nearest-even
  return (unsigned short)(u >> 16);
}
__device__ __forceinline__ float bflo(unsigned w) { return __uint_as_float(w << 16); }
__device__ __forceinline__ float bfhi(unsigned w) { return __uint_as_float(w & 0xffff0000u); }

// ---------------- x -> bf16 conversion ----------------
__global__ __launch_bounds__(256) void xcvt_kernel(const float4* __restrict__ x4,
                                                   ushort4* __restrict__ xb4) {
  int i = blockIdx.x * 256 + threadIdx.x;
  if (i < N_NODES * F_IN / 4) {
    float4 v = x4[i];
    ushort4 o;
    o.x = bf16rn(v.x); o.y = bf16rn(v.y); o.z = bf16rn(v.z); o.w = bf16rn(v.w);
    xb4[i] = o;
  }
}

// ----- pack W1/W2 into MFMA B-fragment order (bf16) -----
// w1p[((nt*2+kf)*64+l)*8+i] = bf16(W1[(l>>4)*8+i+kf*32][nt*16+(l&15)]),  nt<8, kf<2
// w2p[((nt*4+kf)*64+l)*8+i] = bf16(W2[(l>>4)*8+i+kf*32][nt*16+(l&15)]),  nt<3, kf<4 (col>=40 -> 0)
__global__ __launch_bounds__(256) void wpack_kernel(const float* __restrict__ W1,
                                                    const float* __restrict__ W2,
                                                    unsigned short* __restrict__ w1p,
                                                    unsigned short* __restrict__ w2p) {
  int gidx = blockIdx.x * 256 + threadIdx.x;
  if (gidx < 8192) {
    int i = gidx & 7, l = (gidx >> 3) & 63, kf = (gidx >> 9) & 1, nt = gidx >> 10;
    int k = (l >> 4) * 8 + i + kf * 32;
    int c = nt * 16 + (l & 15);
    w1p[gidx] = bf16rn(W1[k * F_HID + c]);
  } else if (gidx < 8192 + 6144) {
    int idx = gidx - 8192;
    int i = idx & 7, l = (idx >> 3) & 63, kf = (idx >> 9) & 3, nt = idx >> 11;
    int k = (l >> 4) * 8 + i + kf * 32;
    int c = nt * 16 + (l & 15);
    w2p[idx] = (c < F_OUT) ? bf16rn(W2[k * F_OUT + c]) : (unsigned short)0;
  }
}

// ---------------- CSR build: histogram ----------------
__global__ __launch_bounds__(256) void hist_kernel(const int* __restrict__ src,
                                                   int* __restrict__ deg) {
  int i = blockIdx.x * 256 + threadIdx.x;
  if (i < N_EDGES) atomicAdd(&deg[src[i]], 1);
}

// ------- scan A: 20 blocks, block-local exclusive scan + block sums -------
__global__ __launch_bounds__(1024) void scanA_kernel(const int4* __restrict__ deg4,
                                                     int4* __restrict__ rs4,
                                                     int* __restrict__ bsum) {
  __shared__ int wsum[16];
  __shared__ int woff[16];
  int tid = threadIdx.x, lane = tid & 63, wid = tid >> 6;
  int i = blockIdx.x * 1024 + tid;
  int4 v = (i < NQ) ? deg4[i] : make_int4(0, 0, 0, 0);
  int tot = v.x + v.y + v.z + v.w;
  int s = tot;
#pragma unroll
  for (int off = 1; off < 64; off <<= 1) {
    int t = __shfl_up(s, off, 64);
    if (lane >= off) s += t;
  }
  if (lane == 63) wsum[wid] = s;
  __syncthreads();
  if (wid == 0) {
    int wv = (lane < 16) ? wsum[lane] : 0;
    int ss = wv;
#pragma unroll
    for (int off = 1; off < 16; off <<= 1) {
      int t = __shfl_up(ss, off, 64);
      if (lane >= off) ss += t;
    }
    if (lane < 16) woff[lane] = ss - wv;
    if (lane == 15) bsum[blockIdx.x] = ss;
  }
  __syncthreads();
  int excl = woff[wid] + (s - tot);
  if (i < NQ) {
    int e0 = excl, e1 = e0 + v.x, e2 = e1 + v.y, e3 = e2 + v.z;
    rs4[i] = make_int4(e0, e1, e2, e3);
  }
}

// --- scan C (merged with B): each block reduces the 20 block sums itself ---
__global__ __launch_bounds__(1024) void scanC_kernel(int4* __restrict__ rs4,
                                                     int4* __restrict__ cur4,
                                                     const int* __restrict__ bsum,
                                                     int* __restrict__ rs) {
  __shared__ int s_off;
  int tid = threadIdx.x;
  if (tid < 64) {
    int v = (tid < 20) ? bsum[tid] : 0;
    int p = (tid < (int)blockIdx.x) ? v : 0;
#pragma unroll
    for (int m = 1; m < 64; m <<= 1) {
      p += __shfl_xor(p, m, 64);
      v += __shfl_xor(v, m, 64);
    }
    if (tid == 0) {
      s_off = p;
      if (blockIdx.x == 19) rs[N_NODES] = v;   // grand total
    }
  }
  __syncthreads();
  int o = s_off;
  int i = blockIdx.x * 1024 + tid;
  if (i < NQ) {
    int4 r = rs4[i];
    r.x += o; r.y += o; r.z += o; r.w += o;
    rs4[i] = r;
    cur4[i] = r;
  }
}

// ------- CSR build: windowed scatter (8 passes, L2-resident write window) -------
__global__ __launch_bounds__(256) void scatter_kernel(
    const int* __restrict__ src, const int* __restrict__ dst,
    const float* __restrict__ vals, int* __restrict__ cur,
    int2* __restrict__ epack) {
  int pass = blockIdx.x / SC_BLOCKS;
  int i = (blockIdx.x - pass * SC_BLOCKS) * 256 + threadIdx.x;
  if (i >= N_EDGES) return;
  int s = src[i];
  if ((unsigned)(s - pass * SC_RANGE) < (unsigned)SC_RANGE) {
    int p = atomicAdd(&cur[s], 1);
    epack[p] = make_int2(dst[i], __float_as_int(vals[i]));
  }
}

// ------ gather1: one wave per row, barrier-free: sxgb[node] = bf16(A@xb row) ------
__global__ __launch_bounds__(256) void gather1_kernel(
    const int* __restrict__ rs, const int2* __restrict__ epack,
    const uint4* __restrict__ xb, uint4* __restrict__ sxgb) {
  int node = (blockIdx.x * 256 + threadIdx.x) >> 6;
  int lane = threadIdx.x & 63;
  if (node >= N_NODES) return;
  int h = lane >> 3;     // 0..7: which of 8 parallel edges
  int fi = lane & 7;     // feature-oct index (feats 8fi..8fi+7)
  int j0 = rs[node], j1 = rs[node + 1];
  float a0 = 0.f, a1 = 0.f, a2 = 0.f, a3 = 0.f;
  float a4 = 0.f, a5 = 0.f, a6 = 0.f, a7 = 0.f;
  int j = j0;
  for (; j + 16 <= j1; j += 16) {   // 16 edges in flight
    int2 e0 = epack[j + h];
    int2 e1 = epack[j + 8 + h];
    uint4 q0 = xb[(size_t)e0.x * 8 + fi];
    uint4 q1 = xb[(size_t)e1.x * 8 + fi];
    float v0 = __int_as_float(e0.y), v1 = __int_as_float(e1.y);
    a0 += v0 * bflo(q0.x); a1 += v0 * bfhi(q0.x);
    a2 += v0 * bflo(q0.y); a3 += v0 * bfhi(q0.y);
    a4 += v0 * bflo(q0.z); a5 += v0 * bfhi(q0.z);
    a6 += v0 * bflo(q0.w); a7 += v0 * bfhi(q0.w);
    a0 += v1 * bflo(q1.x); a1 += v1 * bfhi(q1.x);
    a2 += v1 * bflo(q1.y); a3 += v1 * bfhi(q1.y);
    a4 += v1 * bflo(q1.z); a5 += v1 * bfhi(q1.z);
    a6 += v1 * bflo(q1.w); a7 += v1 * bfhi(q1.w);
  }
  for (; j + 8 <= j1; j += 8) {
    int2 e = epack[j + h];
    uint4 q = xb[(size_t)e.x * 8 + fi];
    float v = __int_as_float(e.y);
    a0 += v * bflo(q.x); a1 += v * bfhi(q.x);
    a2 += v * bflo(q.y); a3 += v * bfhi(q.y);
    a4 += v * bflo(q.z); a5 += v * bfhi(q.z);
    a6 += v * bflo(q.w); a7 += v * bfhi(q.w);
  }
  if (h < j1 - j) {                 // tail 0..7 edges
    int2 e = epack[j + h];
    uint4 q = xb[(size_t)e.x * 8 + fi];
    float v = __int_as_float(e.y);
    a0 += v * bflo(q.x); a1 += v * bfhi(q.x);
    a2 += v * bflo(q.y); a3 += v * bfhi(q.y);
    a4 += v * bflo(q.z); a5 += v * bfhi(q.z);
    a6 += v * bflo(q.w); a7 += v * bfhi(q.w);
  }
#pragma unroll
  for (int m = 8; m <= 32; m <<= 1) {
    a0 += __shfl_xor(a0, m, 64); a1 += __shfl_xor(a1, m, 64);
    a2 += __shfl_xor(a2, m, 64); a3 += __shfl_xor(a3, m, 64);
    a4 += __shfl_xor(a4, m, 64); a5 += __shfl_xor(a5, m, 64);
    a6 += __shfl_xor(a6, m, 64); a7 += __shfl_xor(a7, m, 64);
  }
  if (lane < 8) {
    uint4 o;
    o.x = (unsigned)bf16rn(a0) | ((unsigned)bf16rn(a1) << 16);
    o.y = (unsigned)bf16rn(a2) | ((unsigned)bf16rn(a3) << 16);
    o.z = (unsigned)bf16rn(a4) | ((unsigned)bf16rn(a5) << 16);
    o.w = (unsigned)bf16rn(a6) | ((unsigned)bf16rn(a7) << 16);
    sxgb[(size_t)node * 8 + fi] = o;
  }
}

// ---- dense (MFMA): gb = bf16(relu(sX@W1)@W2), sX = 32 bf16 rows in LDS ----
// 256 thr = 4 waves. Phase1: 2x8 tiles of 16x16 (K=64). Phase2: 2x3 tiles (K=128, N pad 48).
__global__ __launch_bounds__(256) void dense_kernel(
    const uint4* __restrict__ sxgb, const uint4* __restrict__ w1p4,
    const uint4* __restrict__ w2p4, unsigned short* __restrict__ gb) {
  __shared__ __align__(16) unsigned short sA[32 * SAP];   // 4.6 KB
  __shared__ __align__(16) unsigned short sP[32 * SPP];   // 8.7 KB
  int tid = threadIdx.x, lane = tid & 63, w = tid >> 6;
  int rbase = blockIdx.x * 32;

  {                                   // stage 32 rows x 8 uint4, bf16 direct
    int row = tid >> 3, qi = tid & 7;
    uint4 q = sxgb[blockIdx.x * 256 + tid];
    *(uint4*)&sA[row * SAP + qi * 8] = q;
  }
  __syncthreads();

  int kg = lane >> 4;                 // k-group 0..3 (8 k each)
  int cl = lane & 15;                 // col-in-tile / row-in-tile

  // ---- phase 1: P = relu(A @ W1) ----
  {
    int mt = w & 1;                   // row tile
    int ntb = (w >> 1) * 4;           // col tiles ntb..ntb+3
    int arow = mt * 16 + cl;
    bf16x8 a0 = *(const bf16x8*)&sA[arow * SAP + kg * 8];
    bf16x8 a1 = *(const bf16x8*)&sA[arow * SAP + 32 + kg * 8];
    int prow = mt * 16 + kg * 4;
#pragma unroll
    for (int t = 0; t < 4; ++t) {
      int nt = ntb + t;
      f32x4 acc = {0.f, 0.f, 0.f, 0.f};
      bf16x8 b0 = *(const bf16x8*)&w1p4[(nt * 2 + 0) * 64 + lane];
      bf16x8 b1 = *(const bf16x8*)&w1p4[(nt * 2 + 1) * 64 + lane];
      acc = __builtin_amdgcn_mfma_f32_16x16x32_bf16(a0, b0, acc, 0, 0, 0);
      acc = __builtin_amdgcn_mfma_f32_16x16x32_bf16(a1, b1, acc, 0, 0, 0);
      int pcol = nt * 16 + cl;
#pragma unroll
      for (int r = 0; r < 4; ++r)
        sP[(prow + r) * SPP + pcol] = bf16rn(fmaxf(acc[r], 0.f));
    }
  }
  __syncthreads();

  // ---- phase 2: out = P @ W2 (N padded to 48, write cols < 40) ----
  {
    int nT = (w < 2) ? 2 : 1;         // waves 0,1: 2 tiles; waves 2,3: 1 tile
    for (int s = 0; s < nT; ++s) {
      int T = w + s * 4;              // 0..5
      int mt = T & 1, nt = T >> 1;
      int arow = mt * 16 + cl;
      f32x4 acc = {0.f, 0.f, 0.f, 0.f};
#pragma unroll
      for (int kf = 0; kf < 4; ++kf) {
        bf16x8 a = *(const bf16x8*)&sP[arow * SPP + kf * 32 + kg * 8];
        bf16x8 b = *(const bf16x8*)&w2p4[(nt * 4 + kf) * 64 + lane];
        acc = __builtin_amdgcn_mfma_f32_16x16x32_bf16(a, b, acc, 0, 0, 0);
      }
      int ocol = nt * 16 + cl;
      if (ocol < F_OUT) {
        int orow = rbase + mt * 16 + kg * 4;
#pragma unroll
        for (int r = 0; r < 4; ++r)
          gb[(size_t)(orow + r) * F_OUT + ocol] = bf16rn(acc[r]);
      }
    }
  }
}

// ------- SPMM2 gather: out = A @ gb (40 bf16 feats = 5 lanes x uint4) -------
__global__ __launch_bounds__(256) void spmm2_kernel(
    const int* __restrict__ rs, const int2* __restrict__ epack,
    const uint4* __restrict__ gb4, float* __restrict__ out) {
  int node = (blockIdx.x * 256 + threadIdx.x) >> 6;
  int lane = threadIdx.x & 63;
  if (node >= N_NODES) return;
  int grp = lane / 5;         // 0..11 live, 12 = idle (lanes 60-63)
  int fi = lane % 5;          // feature oct (feats 8fi..8fi+7)
  bool active = grp < 12;
  int j0 = rs[node], j1 = rs[node + 1];
  float a0 = 0.f, a1 = 0.f, a2 = 0.f, a3 = 0.f;
  float a4 = 0.f, a5 = 0.f, a6 = 0.f, a7 = 0.f;
  int j = j0;
  for (; j + 24 <= j1; j += 24) {   // 24 edges in flight
    if (active) {
      int2 e0 = epack[j + grp];
      int2 e1 = epack[j + 12 + grp];
      uint4 q0 = gb4[(size_t)e0.x * 5 + fi];
      uint4 q1 = gb4[(size_t)e1.x * 5 + fi];
      float v0 = __int_as_float(e0.y), v1 = __int_as_float(e1.y);
      a0 += v0 * bflo(q0.x); a1 += v0 * bfhi(q0.x);
      a2 += v0 * bflo(q0.y); a3 += v0 * bfhi(q0.y);
      a4 += v0 * bflo(q0.z); a5 += v0 * bfhi(q0.z);
      a6 += v0 * bflo(q0.w); a7 += v0 * bfhi(q0.w);
      a0 += v1 * bflo(q1.x); a1 += v1 * bfhi(q1.x);
      a2 += v1 * bflo(q1.y); a3 += v1 * bfhi(q1.y);
      a4 += v1 * bflo(q1.z); a5 += v1 * bfhi(q1.z);
      a6 += v1 * bflo(q1.w); a7 += v1 * bfhi(q1.w);
    }
  }
  for (; j + 12 <= j1; j += 12) {
    if (active) {
      int2 e = epack[j + grp];
      uint4 q = gb4[(size_t)e.x * 5 + fi];
      float v = __int_as_float(e.y);
      a0 += v * bflo(q.x); a1 += v * bfhi(q.x);
      a2 += v * bflo(q.y); a3 += v * bfhi(q.y);
      a4 += v * bflo(q.z); a5 += v * bfhi(q.z);
      a6 += v * bflo(q.w); a7 += v * bfhi(q.w);
    }
  }
  if (active && grp < j1 - j) {     // tail 0..11 edges
    int2 e = epack[j + grp];
    uint4 q = gb4[(size_t)e.x * 5 + fi];
    float v = __int_as_float(e.y);
    a0 += v * bflo(q.x); a1 += v * bfhi(q.x);
    a2 += v * bflo(q.y); a3 += v * bfhi(q.y);
    a4 += v * bflo(q.z); a5 += v * bfhi(q.z);
    a6 += v * bflo(q.w); a7 += v * bfhi(q.w);
  }
  // merge 12 groups of 5 lanes: +30, +15, then +5 and +10
  float t0, t1, t2, t3, t4, t5, t6, t7;
  t0 = __shfl(a0, lane + 30, 64); t1 = __shfl(a1, lane + 30, 64);
  t2 = __shfl(a2, lane + 30, 64); t3 = __shfl(a3, lane + 30, 64);
  t4 = __shfl(a4, lane + 30, 64); t5 = __shfl(a5, lane + 30, 64);
  t6 = __shfl(a6, lane + 30, 64); t7 = __shfl(a7, lane + 30, 64);
  if (lane < 30) { a0 += t0; a1 += t1; a2 += t2; a3 += t3;
                   a4 += t4; a5 += t5; a6 += t6; a7 += t7; }
  t0 = __shfl(a0, lane + 15, 64); t1 = __shfl(a1, lane + 15, 64);
  t2 = __shfl(a2, lane + 15, 64); t3 = __shfl(a3, lane + 15, 64);
  t4 = __shfl(a4, lane + 15, 64); t5 = __shfl(a5, lane + 15, 64);
  t6 = __shfl(a6, lane + 15, 64); t7 = __shfl(a7, lane + 15, 64);
  if (lane < 15) { a0 += t0; a1 += t1; a2 += t2; a3 += t3;
                   a4 += t4; a5 += t5; a6 += t6; a7 += t7; }
  float u0, u1, u2, u3, u4, u5, u6, u7;
  t0 = __shfl(a0, lane + 5, 64);  t1 = __shfl(a1, lane + 5, 64);
  t2 = __shfl(a2, lane + 5, 64);  t3 = __shfl(a3, lane + 5, 64);
  t4 = __shfl(a4, lane + 5, 64);  t5 = __shfl(a5, lane + 5, 64);
  t6 = __shfl(a6, lane + 5, 64);  t7 = __shfl(a7, lane + 5, 64);
  u0 = __shfl(a0, lane + 10, 64); u1 = __shfl(a1, lane + 10, 64);
  u2 = __shfl(a2, lane + 10, 64); u3 = __shfl(a3, lane + 10, 64);
  u4 = __shfl(a4, lane + 10, 64); u5 = __shfl(a5, lane + 10, 64);
  u6 = __shfl(a6, lane + 10, 64); u7 = __shfl(a7, lane + 10, 64);
  if (lane < 5) {
    a0 += t0 + u0; a1 += t1 + u1; a2 += t2 + u2; a3 += t3 + u3;
    a4 += t4 + u4; a5 += t5 + u5; a6 += t6 + u6; a7 += t7 + u7;
    float4 o0; o0.x = a0; o0.y = a1; o0.z = a2; o0.w = a3;
    float4 o1; o1.x = a4; o1.y = a5; o1.z = a6; o1.w = a7;
    *(float4*)&out[(size_t)node * F_OUT + fi * 8] = o0;
    *(float4*)&out[(size_t)node * F_OUT + fi * 8 + 4] = o1;
  }
}

extern "C" void kernel_launch(void* const* d_in, const int* in_sizes, int n_in,
                              void* d_out, int out_size, void* d_ws, size_t ws_size,
                              hipStream_t stream) {
  const int* src = (const int*)d_in[0];
  const int* dst = (const int*)d_in[1];
  const float* vals = (const float*)d_in[2];
  const float* x = (const float*)d_in[3];
  const float* W1 = (const float*)d_in[4];
  const float* W2 = (const float*)d_in[5];
  float* out = (float*)d_out;

  // 16B-aligned workspace layout (~38.2 MB)
  int* deg = (int*)d_ws;                           // 80000 ints
  int* rs = deg + 80000;                           // 80001 used, pad to 80004
  int* cur = rs + 80004;                           // 80000
  int2* epack = (int2*)(cur + 80000);              // 16B-aligned
  unsigned short* xb = (unsigned short*)(epack + N_EDGES);   // 5.12M bf16
  unsigned short* gb = xb + (size_t)N_NODES * F_IN;          // 3.2M bf16
  unsigned short* sxgb = gb + (size_t)N_NODES * F_OUT;       // 5.12M bf16
  unsigned short* w1p = sxgb + (size_t)N_NODES * F_IN;       // 8192 bf16
  unsigned short* w2p = w1p + 8192;                          // 6144 bf16
  int* bsum = (int*)(w2p + 6144);                            // 20

  hipMemsetAsync(deg, 0, N_NODES * sizeof(int), stream);

  xcvt_kernel<<<(N_NODES * F_IN / 4 + 255) / 256, 256, 0, stream>>>(
      (const float4*)x, (ushort4*)xb);
  wpack_kernel<<<(8192 + 6144 + 255) / 256, 256, 0, stream>>>(W1, W2, w1p, w2p);
  hist_kernel<<<(N_EDGES + 255) / 256, 256, 0, stream>>>(src, deg);
  scanA_kernel<<<20, 1024, 0, stream>>>((const int4*)deg, (int4*)rs, bsum);
  scanC_kernel<<<20, 1024, 0, stream>>>((int4*)rs, (int4*)cur, bsum, rs);
  scatter_kernel<<<SC_PASSES * SC_BLOCKS, 256, 0, stream>>>(src, dst, vals, cur, epack);
  gather1_kernel<<<(N_NODES * 64 + 255) / 256, 256, 0, stream>>>(
      rs, epack, (const uint4*)xb, (uint4*)sxgb);
  dense_kernel<<<N_NODES / 32, 256, 0, stream>>>(
      (const uint4*)sxgb, (const uint4*)w1p, (const uint4*)w2p, gb);
  spmm2_kernel<<<(N_NODES * 64 + 255) / 256, 256, 0, stream>>>(
      rs, epack, (const uint4*)gb, out);
}

// Round 15
// 183.524 us; speedup vs baseline: 1.6694x; 1.2268x over previous
//
#include <hip/hip_runtime.h>

#define N_NODES 80000
#define N_EDGES 1280000
#define F_IN 64
#define F_HID 128
#define F_OUT 40
#define NQ (N_NODES / 4)   // 20000 int4 groups
#define NB 313             // src buckets (src>>8), 256 nodes each
#define B1 320             // edge-chunk blocks
#define CHUNK 4000         // edges per chunk block (320*4000 = 1.28M)
#define SAP 72             // sA bf16 stride (row 64 + pad 8)
#define SPP 136            // sP bf16 stride (row 128 + pad 8)

typedef __attribute__((ext_vector_type(8))) short bf16x8;
typedef __attribute__((ext_vector_type(4))) float f32x4;

__device__ __forceinline__ unsigned short bf16rn(float f) {
  unsigned u = __float_as_uint(f);
  u += 0x7fffu + ((u >> 16) & 1u);   // round-to-nearest-even
  return (unsigned short)(u >> 16);
}
__device__ __forceinline__ float bflo(unsigned w) { return __uint_as_float(w << 16); }
__device__ __forceinline__ float bfhi(unsigned w) { return __uint_as_float(w & 0xffff0000u); }

// ---------------- x -> bf16 conversion ----------------
__global__ __launch_bounds__(256) void xcvt_kernel(const float4* __restrict__ x4,
                                                   ushort4* __restrict__ xb4) {
  int i = blockIdx.x * 256 + threadIdx.x;
  if (i < N_NODES * F_IN / 4) {
    float4 v = x4[i];
    ushort4 o;
    o.x = bf16rn(v.x); o.y = bf16rn(v.y); o.z = bf16rn(v.z); o.w = bf16rn(v.w);
    xb4[i] = o;
  }
}

// ----- pack W1/W2 into MFMA B-fragment order (bf16) -----
__global__ __launch_bounds__(256) void wpack_kernel(const float* __restrict__ W1,
                                                    const float* __restrict__ W2,
                                                    unsigned short* __restrict__ w1p,
                                                    unsigned short* __restrict__ w2p) {
  int gidx = blockIdx.x * 256 + threadIdx.x;
  if (gidx < 8192) {
    int i = gidx & 7, l = (gidx >> 3) & 63, kf = (gidx >> 9) & 1, nt = gidx >> 10;
    int k = (l >> 4) * 8 + i + kf * 32;
    int c = nt * 16 + (l & 15);
    w1p[gidx] = bf16rn(W1[k * F_HID + c]);
  } else if (gidx < 8192 + 6144) {
    int idx = gidx - 8192;
    int i = idx & 7, l = (idx >> 3) & 63, kf = (idx >> 9) & 3, nt = idx >> 11;
    int k = (l >> 4) * 8 + i + kf * 32;
    int c = nt * 16 + (l & 15);
    w2p[idx] = (c < F_OUT) ? bf16rn(W2[k * F_OUT + c]) : (unsigned short)0;
  }
}

// ---- histA: per-node degree (global atomics) + per-(block,bucket) counts ----
__global__ __launch_bounds__(256) void histA_kernel(const int* __restrict__ src,
                                                    int* __restrict__ deg,
                                                    int* __restrict__ counts) {
  __shared__ int h[NB];
  int tid = threadIdx.x;
  for (int i = tid; i < NB; i += 256) h[i] = 0;
  __syncthreads();
  int base = blockIdx.x * CHUNK;
  for (int i = base + tid; i < base + CHUNK; i += 256) {
    int s = src[i];
    atomicAdd(&deg[s], 1);
    atomicAdd(&h[s >> 8], 1);
  }
  __syncthreads();
  for (int i = tid; i < NB; i += 256) counts[blockIdx.x * NB + i] = h[i];
}

// ------- scan A: 20 blocks, block-local exclusive scan + block sums -------
__global__ __launch_bounds__(1024) void scanA_kernel(const int4* __restrict__ deg4,
                                                     int4* __restrict__ rs4,
                                                     int* __restrict__ bsum) {
  __shared__ int wsum[16];
  __shared__ int woff[16];
  int tid = threadIdx.x, lane = tid & 63, wid = tid >> 6;
  int i = blockIdx.x * 1024 + tid;
  int4 v = (i < NQ) ? deg4[i] : make_int4(0, 0, 0, 0);
  int tot = v.x + v.y + v.z + v.w;
  int s = tot;
#pragma unroll
  for (int off = 1; off < 64; off <<= 1) {
    int t = __shfl_up(s, off, 64);
    if (lane >= off) s += t;
  }
  if (lane == 63) wsum[wid] = s;
  __syncthreads();
  if (wid == 0) {
    int wv = (lane < 16) ? wsum[lane] : 0;
    int ss = wv;
#pragma unroll
    for (int off = 1; off < 16; off <<= 1) {
      int t = __shfl_up(ss, off, 64);
      if (lane >= off) ss += t;
    }
    if (lane < 16) woff[lane] = ss - wv;
    if (lane == 15) bsum[blockIdx.x] = ss;
  }
  __syncthreads();
  int excl = woff[wid] + (s - tot);
  if (i < NQ) {
    int e0 = excl, e1 = e0 + v.x, e2 = e1 + v.y, e3 = e2 + v.z;
    rs4[i] = make_int4(e0, e1, e2, e3);
  }
}

// --- scan C: add block offsets (each block reduces the 20 sums itself) ---
__global__ __launch_bounds__(1024) void scanC_kernel(int4* __restrict__ rs4,
                                                     const int* __restrict__ bsum,
                                                     int* __restrict__ rs) {
  __shared__ int s_off;
  int tid = threadIdx.x;
  if (tid < 64) {
    int v = (tid < 20) ? bsum[tid] : 0;
    int p = (tid < (int)blockIdx.x) ? v : 0;
#pragma unroll
    for (int m = 1; m < 64; m <<= 1) {
      p += __shfl_xor(p, m, 64);
      v += __shfl_xor(v, m, 64);
    }
    if (tid == 0) {
      s_off = p;
      if (blockIdx.x == 19) rs[N_NODES] = v;   // grand total
    }
  }
  __syncthreads();
  int o = s_off;
  int i = blockIdx.x * 1024 + tid;
  if (i < NQ) {
    int4 r = rs4[i];
    r.x += o; r.y += o; r.z += o; r.w += o;
    rs4[i] = r;
  }
}

// --- scan2: per bucket b, exclusive-scan the 320 block counts + CSR base ---
__global__ __launch_bounds__(320) void scan2_kernel(int* __restrict__ counts,
                                                    const int* __restrict__ rs) {
  __shared__ int wsum[5];
  __shared__ int woff[5];
  int b = blockIdx.x;
  int t = threadIdx.x, lane = t & 63, w = t >> 6;
  int v = counts[t * NB + b];
  int s = v;
#pragma unroll
  for (int off = 1; off < 64; off <<= 1) {
    int u = __shfl_up(s, off, 64);
    if (lane >= off) s += u;
  }
  if (lane == 63) wsum[w] = s;
  __syncthreads();
  if (t == 0) {
    int acc = 0;
#pragma unroll
    for (int i = 0; i < 5; ++i) { woff[i] = acc; acc += wsum[i]; }
  }
  __syncthreads();
  counts[t * NB + b] = (s - v) + woff[w] + rs[b << 8];
}

// --- place: stream edges into bucket-grouped staging (sequential per-bucket
// streams per block -> full-line writes). Packs local node into dst bits 17..24.
__global__ __launch_bounds__(256) void place_kernel(
    const int* __restrict__ src, const int* __restrict__ dst,
    const float* __restrict__ vals, const int* __restrict__ off,
    int2* __restrict__ estg) {
  __shared__ int cur[NB];
  int tid = threadIdx.x;
  for (int i = tid; i < NB; i += 256) cur[i] = off[blockIdx.x * NB + i];
  __syncthreads();
  int base = blockIdx.x * CHUNK;
  for (int i = base + tid; i < base + CHUNK; i += 256) {
    int s = src[i];
    int p = atomicAdd(&cur[s >> 8], 1);
    estg[p] = make_int2(dst[i] | ((s & 255) << 17), __float_as_int(vals[i]));
  }
}

// --- permute: one block per bucket; scatter staged bucket to final CSR slots.
// All writes from one block (one XCD) within a ~32KB window -> L2-local.
__global__ __launch_bounds__(256) void permute_kernel(const int* __restrict__ rs,
                                                      const int2* __restrict__ estg,
                                                      int2* __restrict__ epack) {
  __shared__ int curl[256];
  int b = blockIdx.x, tid = threadIdx.x;
  int nb0 = b << 8;
  int nb1 = min(nb0 + 256, N_NODES);
  if (tid < nb1 - nb0) curl[tid] = rs[nb0 + tid];
  __syncthreads();
  int ebase = rs[nb0], eend = rs[nb1];
  for (int e = ebase + tid; e < eend; e += 256) {
    int2 v = estg[e];
    int p = atomicAdd(&curl[(v.x >> 17) & 255], 1);
    epack[p] = make_int2(v.x & 0x1FFFF, v.y);
  }
}

// ------ gather1: one wave per row, barrier-free: sxgb[node] = bf16(A@xb row) ------
__global__ __launch_bounds__(256) void gather1_kernel(
    const int* __restrict__ rs, const int2* __restrict__ epack,
    const uint4* __restrict__ xb, uint4* __restrict__ sxgb) {
  int node = (blockIdx.x * 256 + threadIdx.x) >> 6;
  int lane = threadIdx.x & 63;
  if (node >= N_NODES) return;
  int h = lane >> 3;     // 0..7: which of 8 parallel edges
  int fi = lane & 7;     // feature-oct index (feats 8fi..8fi+7)
  int j0 = rs[node], j1 = rs[node + 1];
  float a0 = 0.f, a1 = 0.f, a2 = 0.f, a3 = 0.f;
  float a4 = 0.f, a5 = 0.f, a6 = 0.f, a7 = 0.f;
  int j = j0;
  for (; j + 16 <= j1; j += 16) {   // 16 edges in flight
    int2 e0 = epack[j + h];
    int2 e1 = epack[j + 8 + h];
    uint4 q0 = xb[(size_t)e0.x * 8 + fi];
    uint4 q1 = xb[(size_t)e1.x * 8 + fi];
    float v0 = __int_as_float(e0.y), v1 = __int_as_float(e1.y);
    a0 += v0 * bflo(q0.x); a1 += v0 * bfhi(q0.x);
    a2 += v0 * bflo(q0.y); a3 += v0 * bfhi(q0.y);
    a4 += v0 * bflo(q0.z); a5 += v0 * bfhi(q0.z);
    a6 += v0 * bflo(q0.w); a7 += v0 * bfhi(q0.w);
    a0 += v1 * bflo(q1.x); a1 += v1 * bfhi(q1.x);
    a2 += v1 * bflo(q1.y); a3 += v1 * bfhi(q1.y);
    a4 += v1 * bflo(q1.z); a5 += v1 * bfhi(q1.z);
    a6 += v1 * bflo(q1.w); a7 += v1 * bfhi(q1.w);
  }
  for (; j + 8 <= j1; j += 8) {
    int2 e = epack[j + h];
    uint4 q = xb[(size_t)e.x * 8 + fi];
    float v = __int_as_float(e.y);
    a0 += v * bflo(q.x); a1 += v * bfhi(q.x);
    a2 += v * bflo(q.y); a3 += v * bfhi(q.y);
    a4 += v * bflo(q.z); a5 += v * bfhi(q.z);
    a6 += v * bflo(q.w); a7 += v * bfhi(q.w);
  }
  if (h < j1 - j) {                 // tail 0..7 edges
    int2 e = epack[j + h];
    uint4 q = xb[(size_t)e.x * 8 + fi];
    float v = __int_as_float(e.y);
    a0 += v * bflo(q.x); a1 += v * bfhi(q.x);
    a2 += v * bflo(q.y); a3 += v * bfhi(q.y);
    a4 += v * bflo(q.z); a5 += v * bfhi(q.z);
    a6 += v * bflo(q.w); a7 += v * bfhi(q.w);
  }
#pragma unroll
  for (int m = 8; m <= 32; m <<= 1) {
    a0 += __shfl_xor(a0, m, 64); a1 += __shfl_xor(a1, m, 64);
    a2 += __shfl_xor(a2, m, 64); a3 += __shfl_xor(a3, m, 64);
    a4 += __shfl_xor(a4, m, 64); a5 += __shfl_xor(a5, m, 64);
    a6 += __shfl_xor(a6, m, 64); a7 += __shfl_xor(a7, m, 64);
  }
  if (lane < 8) {
    uint4 o;
    o.x = (unsigned)bf16rn(a0) | ((unsigned)bf16rn(a1) << 16);
    o.y = (unsigned)bf16rn(a2) | ((unsigned)bf16rn(a3) << 16);
    o.z = (unsigned)bf16rn(a4) | ((unsigned)bf16rn(a5) << 16);
    o.w = (unsigned)bf16rn(a6) | ((unsigned)bf16rn(a7) << 16);
    sxgb[(size_t)node * 8 + fi] = o;
  }
}

// ---- dense (MFMA): gb = bf16(relu(sX@W1)@W2), sX = 32 bf16 rows in LDS ----
__global__ __launch_bounds__(256) void dense_kernel(
    const uint4* __restrict__ sxgb, const uint4* __restrict__ w1p4,
    const uint4* __restrict__ w2p4, unsigned short* __restrict__ gb) {
  __shared__ __align__(16) unsigned short sA[32 * SAP];   // 4.6 KB
  __shared__ __align__(16) unsigned short sP[32 * SPP];   // 8.7 KB
  int tid = threadIdx.x, lane = tid & 63, w = tid >> 6;
  int rbase = blockIdx.x * 32;

  {                                   // stage 32 rows x 8 uint4, bf16 direct
    int row = tid >> 3, qi = tid & 7;
    uint4 q = sxgb[blockIdx.x * 256 + tid];
    *(uint4*)&sA[row * SAP + qi * 8] = q;
  }
  __syncthreads();

  int kg = lane >> 4;                 // k-group 0..3 (8 k each)
  int cl = lane & 15;                 // col-in-tile / row-in-tile

  // ---- phase 1: P = relu(A @ W1) ----
  {
    int mt = w & 1;                   // row tile
    int ntb = (w >> 1) * 4;           // col tiles ntb..ntb+3
    int arow = mt * 16 + cl;
    bf16x8 a0 = *(const bf16x8*)&sA[arow * SAP + kg * 8];
    bf16x8 a1 = *(const bf16x8*)&sA[arow * SAP + 32 + kg * 8];
    int prow = mt * 16 + kg * 4;
#pragma unroll
    for (int t = 0; t < 4; ++t) {
      int nt = ntb + t;
      f32x4 acc = {0.f, 0.f, 0.f, 0.f};
      bf16x8 b0 = *(const bf16x8*)&w1p4[(nt * 2 + 0) * 64 + lane];
      bf16x8 b1 = *(const bf16x8*)&w1p4[(nt * 2 + 1) * 64 + lane];
      acc = __builtin_amdgcn_mfma_f32_16x16x32_bf16(a0, b0, acc, 0, 0, 0);
      acc = __builtin_amdgcn_mfma_f32_16x16x32_bf16(a1, b1, acc, 0, 0, 0);
      int pcol = nt * 16 + cl;
#pragma unroll
      for (int r = 0; r < 4; ++r)
        sP[(prow + r) * SPP + pcol] = bf16rn(fmaxf(acc[r], 0.f));
    }
  }
  __syncthreads();

  // ---- phase 2: out = P @ W2 (N padded to 48, write cols < 40) ----
  {
    int nT = (w < 2) ? 2 : 1;         // waves 0,1: 2 tiles; waves 2,3: 1 tile
    for (int s = 0; s < nT; ++s) {
      int T = w + s * 4;              // 0..5
      int mt = T & 1, nt = T >> 1;
      int arow = mt * 16 + cl;
      f32x4 acc = {0.f, 0.f, 0.f, 0.f};
#pragma unroll
      for (int kf = 0; kf < 4; ++kf) {
        bf16x8 a = *(const bf16x8*)&sP[arow * SPP + kf * 32 + kg * 8];
        bf16x8 b = *(const bf16x8*)&w2p4[(nt * 4 + kf) * 64 + lane];
        acc = __builtin_amdgcn_mfma_f32_16x16x32_bf16(a, b, acc, 0, 0, 0);
      }
      int ocol = nt * 16 + cl;
      if (ocol < F_OUT) {
        int orow = rbase + mt * 16 + kg * 4;
#pragma unroll
        for (int r = 0; r < 4; ++r)
          gb[(size_t)(orow + r) * F_OUT + ocol] = bf16rn(acc[r]);
      }
    }
  }
}

// ------- SPMM2 gather: out = A @ gb (40 bf16 feats = 5 lanes x uint4) -------
__global__ __launch_bounds__(256) void spmm2_kernel(
    const int* __restrict__ rs, const int2* __restrict__ epack,
    const uint4* __restrict__ gb4, float* __restrict__ out) {
  int node = (blockIdx.x * 256 + threadIdx.x) >> 6;
  int lane = threadIdx.x & 63;
  if (node >= N_NODES) return;
  int grp = lane / 5;         // 0..11 live, 12 = idle (lanes 60-63)
  int fi = lane % 5;          // feature oct (feats 8fi..8fi+7)
  bool active = grp < 12;
  int j0 = rs[node], j1 = rs[node + 1];
  float a0 = 0.f, a1 = 0.f, a2 = 0.f, a3 = 0.f;
  float a4 = 0.f, a5 = 0.f, a6 = 0.f, a7 = 0.f;
  int j = j0;
  for (; j + 24 <= j1; j += 24) {   // 24 edges in flight
    if (active) {
      int2 e0 = epack[j + grp];
      int2 e1 = epack[j + 12 + grp];
      uint4 q0 = gb4[(size_t)e0.x * 5 + fi];
      uint4 q1 = gb4[(size_t)e1.x * 5 + fi];
      float v0 = __int_as_float(e0.y), v1 = __int_as_float(e1.y);
      a0 += v0 * bflo(q0.x); a1 += v0 * bfhi(q0.x);
      a2 += v0 * bflo(q0.y); a3 += v0 * bfhi(q0.y);
      a4 += v0 * bflo(q0.z); a5 += v0 * bfhi(q0.z);
      a6 += v0 * bflo(q0.w); a7 += v0 * bfhi(q0.w);
      a0 += v1 * bflo(q1.x); a1 += v1 * bfhi(q1.x);
      a2 += v1 * bflo(q1.y); a3 += v1 * bfhi(q1.y);
      a4 += v1 * bflo(q1.z); a5 += v1 * bfhi(q1.z);
      a6 += v1 * bflo(q1.w); a7 += v1 * bfhi(q1.w);
    }
  }
  for (; j + 12 <= j1; j += 12) {
    if (active) {
      int2 e = epack[j + grp];
      uint4 q = gb4[(size_t)e.x * 5 + fi];
      float v = __int_as_float(e.y);
      a0 += v * bflo(q.x); a1 += v * bfhi(q.x);
      a2 += v * bflo(q.y); a3 += v * bfhi(q.y);
      a4 += v * bflo(q.z); a5 += v * bfhi(q.z);
      a6 += v * bflo(q.w); a7 += v * bfhi(q.w);
    }
  }
  if (active && grp < j1 - j) {     // tail 0..11 edges
    int2 e = epack[j + grp];
    uint4 q = gb4[(size_t)e.x * 5 + fi];
    float v = __int_as_float(e.y);
    a0 += v * bflo(q.x); a1 += v * bfhi(q.x);
    a2 += v * bflo(q.y); a3 += v * bfhi(q.y);
    a4 += v * bflo(q.z); a5 += v * bfhi(q.z);
    a6 += v * bflo(q.w); a7 += v * bfhi(q.w);
  }
  // merge 12 groups of 5 lanes: +30, +15, then +5 and +10
  float t0, t1, t2, t3, t4, t5, t6, t7;
  t0 = __shfl(a0, lane + 30, 64); t1 = __shfl(a1, lane + 30, 64);
  t2 = __shfl(a2, lane + 30, 64); t3 = __shfl(a3, lane + 30, 64);
  t4 = __shfl(a4, lane + 30, 64); t5 = __shfl(a5, lane + 30, 64);
  t6 = __shfl(a6, lane + 30, 64); t7 = __shfl(a7, lane + 30, 64);
  if (lane < 30) { a0 += t0; a1 += t1; a2 += t2; a3 += t3;
                   a4 += t4; a5 += t5; a6 += t6; a7 += t7; }
  t0 = __shfl(a0, lane + 15, 64); t1 = __shfl(a1, lane + 15, 64);
  t2 = __shfl(a2, lane + 15, 64); t3 = __shfl(a3, lane + 15, 64);
  t4 = __shfl(a4, lane + 15, 64); t5 = __shfl(a5, lane + 15, 64);
  t6 = __shfl(a6, lane + 15, 64); t7 = __shfl(a7, lane + 15, 64);
  if (lane < 15) { a0 += t0; a1 += t1; a2 += t2; a3 += t3;
                   a4 += t4; a5 += t5; a6 += t6; a7 += t7; }
  float u0, u1, u2, u3, u4, u5, u6, u7;
  t0 = __shfl(a0, lane + 5, 64);  t1 = __shfl(a1, lane + 5, 64);
  t2 = __shfl(a2, lane + 5, 64);  t3 = __shfl(a3, lane + 5, 64);
  t4 = __shfl(a4, lane + 5, 64);  t5 = __shfl(a5, lane + 5, 64);
  t6 = __shfl(a6, lane + 5, 64);  t7 = __shfl(a7, lane + 5, 64);
  u0 = __shfl(a0, lane + 10, 64); u1 = __shfl(a1, lane + 10, 64);
  u2 = __shfl(a2, lane + 10, 64); u3 = __shfl(a3, lane + 10, 64);
  u4 = __shfl(a4, lane + 10, 64); u5 = __shfl(a5, lane + 10, 64);
  u6 = __shfl(a6, lane + 10, 64); u7 = __shfl(a7, lane + 10, 64);
  if (lane < 5) {
    a0 += t0 + u0; a1 += t1 + u1; a2 += t2 + u2; a3 += t3 + u3;
    a4 += t4 + u4; a5 += t5 + u5; a6 += t6 + u6; a7 += t7 + u7;
    float4 o0; o0.x = a0; o0.y = a1; o0.z = a2; o0.w = a3;
    float4 o1; o1.x = a4; o1.y = a5; o1.z = a6; o1.w = a7;
    *(float4*)&out[(size_t)node * F_OUT + fi * 8] = o0;
    *(float4*)&out[(size_t)node * F_OUT + fi * 8 + 4] = o1;
  }
}

extern "C" void kernel_launch(void* const* d_in, const int* in_sizes, int n_in,
                              void* d_out, int out_size, void* d_ws, size_t ws_size,
                              hipStream_t stream) {
  const int* src = (const int*)d_in[0];
  const int* dst = (const int*)d_in[1];
  const float* vals = (const float*)d_in[2];
  const float* x = (const float*)d_in[3];
  const float* W1 = (const float*)d_in[4];
  const float* W2 = (const float*)d_in[5];
  float* out = (float*)d_out;

  // 16B-aligned workspace layout (~38.3 MB)
  int* deg = (int*)d_ws;                           // 80000 ints
  int* rs = deg + 80000;                           // 80001 used, pad to 80004
  int* counts = rs + 80004;                        // 320*313 = 100160 ints
  int2* epack = (int2*)(counts + 100160);          // 16B-aligned (260164*4 B)
  unsigned short* xb = (unsigned short*)(epack + N_EDGES);   // 5.12M bf16
  unsigned short* gb = xb + (size_t)N_NODES * F_IN;          // 3.2M bf16
  unsigned short* sxgb = gb + (size_t)N_NODES * F_OUT;       // 5.12M bf16 (also estg)
  unsigned short* w1p = sxgb + (size_t)N_NODES * F_IN;       // 8192 bf16
  unsigned short* w2p = w1p + 8192;                          // 6144 bf16
  int* bsum = (int*)(w2p + 6144);                            // 20
  int2* estg = (int2*)sxgb;   // staging aliases sxgb (dead until gather1)

  hipMemsetAsync(deg, 0, N_NODES * sizeof(int), stream);

  xcvt_kernel<<<(N_NODES * F_IN / 4 + 255) / 256, 256, 0, stream>>>(
      (const float4*)x, (ushort4*)xb);
  wpack_kernel<<<(8192 + 6144 + 255) / 256, 256, 0, stream>>>(W1, W2, w1p, w2p);
  histA_kernel<<<B1, 256, 0, stream>>>(src, deg, counts);
  scanA_kernel<<<20, 1024, 0, stream>>>((const int4*)deg, (int4*)rs, bsum);
  scanC_kernel<<<20, 1024, 0, stream>>>((int4*)rs, bsum, rs);
  scan2_kernel<<<NB, 320, 0, stream>>>(counts, rs);
  place_kernel<<<B1, 256, 0, stream>>>(src, dst, vals, counts, estg);
  permute_kernel<<<NB, 256, 0, stream>>>(rs, estg, epack);
  gather1_kernel<<<(N_NODES * 64 + 255) / 256, 256, 0, stream>>>(
      rs, epack, (const uint4*)xb, (uint4*)sxgb);
  dense_kernel<<<N_NODES / 32, 256, 0, stream>>>(
      (const uint4*)sxgb, (const uint4*)w1p, (const uint4*)w2p, gb);
  spmm2_kernel<<<(N_NODES * 64 + 255) / 256, 256, 0, stream>>>(
      rs, epack, (const uint4*)gb, out);
}

// Round 16
// 130.631 us; speedup vs baseline: 2.3453x; 1.4049x over previous
//
#include <hip/hip_runtime.h>

#define N_NODES 80000
#define N_EDGES 1280000
#define F_IN 64
#define F_HID 128
#define F_OUT 40
#define NB 313             // src buckets (src>>8), 256 nodes each
#define B1 320             // edge-chunk blocks
#define CHUNK 4000         // edges per chunk block (320*4000 = 1.28M)
#define SAP 72             // sA bf16 stride (row 64 + pad 8)
#define SPP 136            // sP bf16 stride (row 128 + pad 8)

typedef __attribute__((ext_vector_type(8))) short bf16x8;
typedef __attribute__((ext_vector_type(4))) float f32x4;

__device__ __forceinline__ unsigned short bf16rn(float f) {
  unsigned u = __float_as_uint(f);
  u += 0x7fffu + ((u >> 16) & 1u);   // round-to-nearest-even
  return (unsigned short)(u >> 16);
}
__device__ __forceinline__ float bflo(unsigned w) { return __uint_as_float(w << 16); }
__device__ __forceinline__ float bfhi(unsigned w) { return __uint_as_float(w & 0xffff0000u); }

// ---------------- x -> bf16 conversion ----------------
__global__ __launch_bounds__(256) void xcvt_kernel(const float4* __restrict__ x4,
                                                   ushort4* __restrict__ xb4) {
  int i = blockIdx.x * 256 + threadIdx.x;
  if (i < N_NODES * F_IN / 4) {
    float4 v = x4[i];
    ushort4 o;
    o.x = bf16rn(v.x); o.y = bf16rn(v.y); o.z = bf16rn(v.z); o.w = bf16rn(v.w);
    xb4[i] = o;
  }
}

// ----- pack W1/W2 into MFMA B-fragment order (bf16) -----
__global__ __launch_bounds__(256) void wpack_kernel(const float* __restrict__ W1,
                                                    const float* __restrict__ W2,
                                                    unsigned short* __restrict__ w1p,
                                                    unsigned short* __restrict__ w2p) {
  int gidx = blockIdx.x * 256 + threadIdx.x;
  if (gidx < 8192) {
    int i = gidx & 7, l = (gidx >> 3) & 63, kf = (gidx >> 9) & 1, nt = gidx >> 10;
    int k = (l >> 4) * 8 + i + kf * 32;
    int c = nt * 16 + (l & 15);
    w1p[gidx] = bf16rn(W1[k * F_HID + c]);
  } else if (gidx < 8192 + 6144) {
    int idx = gidx - 8192;
    int i = idx & 7, l = (idx >> 3) & 63, kf = (idx >> 9) & 3, nt = idx >> 11;
    int k = (l >> 4) * 8 + i + kf * 32;
    int c = nt * 16 + (l & 15);
    w2p[idx] = (c < F_OUT) ? bf16rn(W2[k * F_OUT + c]) : (unsigned short)0;
  }
}

// ---- histB: per-(block,bucket) counts only (LDS histogram, NO global atomics) ----
__global__ __launch_bounds__(256) void histB_kernel(const int* __restrict__ src,
                                                    int* __restrict__ counts) {
  __shared__ int h[NB];
  int tid = threadIdx.x;
  for (int i = tid; i < NB; i += 256) h[i] = 0;
  __syncthreads();
  int base = blockIdx.x * CHUNK;
  for (int i = base + tid; i < base + CHUNK; i += 256)
    atomicAdd(&h[src[i] >> 8], 1);
  __syncthreads();
  for (int i = tid; i < NB; i += 256) counts[blockIdx.x * NB + i] = h[i];
}

// --- scan2: per bucket b, exclusive-scan the 320 block counts; emit bucket total ---
__global__ __launch_bounds__(320) void scan2_kernel(int* __restrict__ counts,
                                                    int* __restrict__ btot) {
  __shared__ int wsum[5];
  __shared__ int woff[5];
  int b = blockIdx.x;
  int t = threadIdx.x, lane = t & 63, w = t >> 6;
  int v = counts[t * NB + b];
  int s = v;
#pragma unroll
  for (int off = 1; off < 64; off <<= 1) {
    int u = __shfl_up(s, off, 64);
    if (lane >= off) s += u;
  }
  if (lane == 63) wsum[w] = s;
  __syncthreads();
  if (t == 0) {
    int acc = 0;
#pragma unroll
    for (int i = 0; i < 5; ++i) { woff[i] = acc; acc += wsum[i]; }
    btot[b] = acc;
  }
  __syncthreads();
  counts[t * NB + b] = (s - v) + woff[w];
}

// --- scanT: one tiny block scans the 313 bucket totals -> bbase ---
__global__ __launch_bounds__(320) void scanT_kernel(const int* __restrict__ btot,
                                                    int* __restrict__ bbase,
                                                    int* __restrict__ rs) {
  __shared__ int wsum[5];
  __shared__ int woff[5];
  int t = threadIdx.x, lane = t & 63, w = t >> 6;
  int v = (t < NB) ? btot[t] : 0;
  int s = v;
#pragma unroll
  for (int off = 1; off < 64; off <<= 1) {
    int u = __shfl_up(s, off, 64);
    if (lane >= off) s += u;
  }
  if (lane == 63) wsum[w] = s;
  __syncthreads();
  if (t == 0) {
    int acc = 0;
#pragma unroll
    for (int i = 0; i < 5; ++i) { woff[i] = acc; acc += wsum[i]; }
  }
  __syncthreads();
  if (t < NB) bbase[t] = (s - v) + woff[w];
  if (t == 0) { bbase[NB] = N_EDGES; rs[N_NODES] = N_EDGES; }
}

// --- place: stream edges into bucket-grouped staging (sequential per-bucket
// streams per block -> mostly full-line writes). Local node in dst bits 17..24.
__global__ __launch_bounds__(256) void place_kernel(
    const int* __restrict__ src, const int* __restrict__ dst,
    const float* __restrict__ vals, const int* __restrict__ off,
    const int* __restrict__ bbase, int2* __restrict__ estg) {
  __shared__ int cur[NB];
  int tid = threadIdx.x;
  for (int i = tid; i < NB; i += 256)
    cur[i] = off[blockIdx.x * NB + i] + bbase[i];
  __syncthreads();
  int base = blockIdx.x * CHUNK;
  for (int i = base + tid; i < base + CHUNK; i += 256) {
    int s = src[i];
    int p = atomicAdd(&cur[s >> 8], 1);
    estg[p] = make_int2(dst[i] | ((s & 255) << 17), __float_as_int(vals[i]));
  }
}

// --- permute: one block per bucket. Pass 1: per-node degree count + block scan
// -> writes rs for its 256 nodes. Pass 2: scatter staged edges to final slots.
// All epack writes from one block (one XCD) in a ~32KB window -> L2-local.
__global__ __launch_bounds__(512) void permute_kernel(const int* __restrict__ bbase,
                                                      const int2* __restrict__ estg,
                                                      int2* __restrict__ epack,
                                                      int* __restrict__ rs) {
  __shared__ int cnt[256];
  __shared__ int cur[256];
  __shared__ int wsum[4];
  __shared__ int woff[4];
  int b = blockIdx.x, tid = threadIdx.x;
  int nb0 = b << 8;
  int ebase = bbase[b], eend = bbase[b + 1];
  if (tid < 256) cnt[tid] = 0;
  __syncthreads();
  for (int e = ebase + tid; e < eend; e += 512) {
    int2 v = estg[e];
    atomicAdd(&cnt[(v.x >> 17) & 255], 1);
  }
  __syncthreads();
  int lane = tid & 63, w = tid >> 6;
  int v = (tid < 256) ? cnt[tid] : 0;
  int s = v;
#pragma unroll
  for (int off = 1; off < 64; off <<= 1) {
    int u = __shfl_up(s, off, 64);
    if (lane >= off) s += u;
  }
  if (tid < 256 && lane == 63) wsum[w] = s;
  __syncthreads();
  if (tid == 0) {
    int acc = 0;
#pragma unroll
    for (int i = 0; i < 4; ++i) { woff[i] = acc; acc += wsum[i]; }
  }
  __syncthreads();
  if (tid < 256) {
    int g = ebase + woff[w] + (s - v);
    if (nb0 + tid < N_NODES) rs[nb0 + tid] = g;
    cur[tid] = g;
  }
  __syncthreads();
  for (int e = ebase + tid; e < eend; e += 512) {
    int2 v2 = estg[e];
    int p = atomicAdd(&cur[(v2.x >> 17) & 255], 1);
    epack[p] = make_int2(v2.x & 0x1FFFF, v2.y);
  }
}

// ------ gather1: one wave per row, barrier-free: sxgb[node] = bf16(A@xb row) ------
__global__ __launch_bounds__(256) void gather1_kernel(
    const int* __restrict__ rs, const int2* __restrict__ epack,
    const uint4* __restrict__ xb, uint4* __restrict__ sxgb) {
  int node = (blockIdx.x * 256 + threadIdx.x) >> 6;
  int lane = threadIdx.x & 63;
  if (node >= N_NODES) return;
  int h = lane >> 3;     // 0..7: which of 8 parallel edges
  int fi = lane & 7;     // feature-oct index (feats 8fi..8fi+7)
  int j0 = rs[node], j1 = rs[node + 1];
  float a0 = 0.f, a1 = 0.f, a2 = 0.f, a3 = 0.f;
  float a4 = 0.f, a5 = 0.f, a6 = 0.f, a7 = 0.f;
  int j = j0;
  for (; j + 16 <= j1; j += 16) {   // 16 edges in flight
    int2 e0 = epack[j + h];
    int2 e1 = epack[j + 8 + h];
    uint4 q0 = xb[(size_t)e0.x * 8 + fi];
    uint4 q1 = xb[(size_t)e1.x * 8 + fi];
    float v0 = __int_as_float(e0.y), v1 = __int_as_float(e1.y);
    a0 += v0 * bflo(q0.x); a1 += v0 * bfhi(q0.x);
    a2 += v0 * bflo(q0.y); a3 += v0 * bfhi(q0.y);
    a4 += v0 * bflo(q0.z); a5 += v0 * bfhi(q0.z);
    a6 += v0 * bflo(q0.w); a7 += v0 * bfhi(q0.w);
    a0 += v1 * bflo(q1.x); a1 += v1 * bfhi(q1.x);
    a2 += v1 * bflo(q1.y); a3 += v1 * bfhi(q1.y);
    a4 += v1 * bflo(q1.z); a5 += v1 * bfhi(q1.z);
    a6 += v1 * bflo(q1.w); a7 += v1 * bfhi(q1.w);
  }
  for (; j + 8 <= j1; j += 8) {
    int2 e = epack[j + h];
    uint4 q = xb[(size_t)e.x * 8 + fi];
    float v = __int_as_float(e.y);
    a0 += v * bflo(q.x); a1 += v * bfhi(q.x);
    a2 += v * bflo(q.y); a3 += v * bfhi(q.y);
    a4 += v * bflo(q.z); a5 += v * bfhi(q.z);
    a6 += v * bflo(q.w); a7 += v * bfhi(q.w);
  }
  if (h < j1 - j) {                 // tail 0..7 edges
    int2 e = epack[j + h];
    uint4 q = xb[(size_t)e.x * 8 + fi];
    float v = __int_as_float(e.y);
    a0 += v * bflo(q.x); a1 += v * bfhi(q.x);
    a2 += v * bflo(q.y); a3 += v * bfhi(q.y);
    a4 += v * bflo(q.z); a5 += v * bfhi(q.z);
    a6 += v * bflo(q.w); a7 += v * bfhi(q.w);
  }
#pragma unroll
  for (int m = 8; m <= 32; m <<= 1) {
    a0 += __shfl_xor(a0, m, 64); a1 += __shfl_xor(a1, m, 64);
    a2 += __shfl_xor(a2, m, 64); a3 += __shfl_xor(a3, m, 64);
    a4 += __shfl_xor(a4, m, 64); a5 += __shfl_xor(a5, m, 64);
    a6 += __shfl_xor(a6, m, 64); a7 += __shfl_xor(a7, m, 64);
  }
  if (lane < 8) {
    uint4 o;
    o.x = (unsigned)bf16rn(a0) | ((unsigned)bf16rn(a1) << 16);
    o.y = (unsigned)bf16rn(a2) | ((unsigned)bf16rn(a3) << 16);
    o.z = (unsigned)bf16rn(a4) | ((unsigned)bf16rn(a5) << 16);
    o.w = (unsigned)bf16rn(a6) | ((unsigned)bf16rn(a7) << 16);
    sxgb[(size_t)node * 8 + fi] = o;
  }
}

// ---- dense (MFMA): gb = bf16(relu(sX@W1)@W2), sX = 32 bf16 rows in LDS ----
__global__ __launch_bounds__(256) void dense_kernel(
    const uint4* __restrict__ sxgb, const uint4* __restrict__ w1p4,
    const uint4* __restrict__ w2p4, unsigned short* __restrict__ gb) {
  __shared__ __align__(16) unsigned short sA[32 * SAP];   // 4.6 KB
  __shared__ __align__(16) unsigned short sP[32 * SPP];   // 8.7 KB
  int tid = threadIdx.x, lane = tid & 63, w = tid >> 6;
  int rbase = blockIdx.x * 32;

  {                                   // stage 32 rows x 8 uint4, bf16 direct
    int row = tid >> 3, qi = tid & 7;
    uint4 q = sxgb[blockIdx.x * 256 + tid];
    *(uint4*)&sA[row * SAP + qi * 8] = q;
  }
  __syncthreads();

  int kg = lane >> 4;                 // k-group 0..3 (8 k each)
  int cl = lane & 15;                 // col-in-tile / row-in-tile

  // ---- phase 1: P = relu(A @ W1) ----
  {
    int mt = w & 1;                   // row tile
    int ntb = (w >> 1) * 4;           // col tiles ntb..ntb+3
    int arow = mt * 16 + cl;
    bf16x8 a0 = *(const bf16x8*)&sA[arow * SAP + kg * 8];
    bf16x8 a1 = *(const bf16x8*)&sA[arow * SAP + 32 + kg * 8];
    int prow = mt * 16 + kg * 4;
#pragma unroll
    for (int t = 0; t < 4; ++t) {
      int nt = ntb + t;
      f32x4 acc = {0.f, 0.f, 0.f, 0.f};
      bf16x8 b0 = *(const bf16x8*)&w1p4[(nt * 2 + 0) * 64 + lane];
      bf16x8 b1 = *(const bf16x8*)&w1p4[(nt * 2 + 1) * 64 + lane];
      acc = __builtin_amdgcn_mfma_f32_16x16x32_bf16(a0, b0, acc, 0, 0, 0);
      acc = __builtin_amdgcn_mfma_f32_16x16x32_bf16(a1, b1, acc, 0, 0, 0);
      int pcol = nt * 16 + cl;
#pragma unroll
      for (int r = 0; r < 4; ++r)
        sP[(prow + r) * SPP + pcol] = bf16rn(fmaxf(acc[r], 0.f));
    }
  }
  __syncthreads();

  // ---- phase 2: out = P @ W2 (N padded to 48, write cols < 40) ----
  {
    int nT = (w < 2) ? 2 : 1;         // waves 0,1: 2 tiles; waves 2,3: 1 tile
    for (int s = 0; s < nT; ++s) {
      int T = w + s * 4;              // 0..5
      int mt = T & 1, nt = T >> 1;
      int arow = mt * 16 + cl;
      f32x4 acc = {0.f, 0.f, 0.f, 0.f};
#pragma unroll
      for (int kf = 0; kf < 4; ++kf) {
        bf16x8 a = *(const bf16x8*)&sP[arow * SPP + kf * 32 + kg * 8];
        bf16x8 b = *(const bf16x8*)&w2p4[(nt * 4 + kf) * 64 + lane];
        acc = __builtin_amdgcn_mfma_f32_16x16x32_bf16(a, b, acc, 0, 0, 0);
      }
      int ocol = nt * 16 + cl;
      if (ocol < F_OUT) {
        int orow = rbase + mt * 16 + kg * 4;
#pragma unroll
        for (int r = 0; r < 4; ++r)
          gb[(size_t)(orow + r) * F_OUT + ocol] = bf16rn(acc[r]);
      }
    }
  }
}

// ------- SPMM2 gather: out = A @ gb (40 bf16 feats = 5 lanes x uint4) -------
__global__ __launch_bounds__(256) void spmm2_kernel(
    const int* __restrict__ rs, const int2* __restrict__ epack,
    const uint4* __restrict__ gb4, float* __restrict__ out) {
  int node = (blockIdx.x * 256 + threadIdx.x) >> 6;
  int lane = threadIdx.x & 63;
  if (node >= N_NODES) return;
  int grp = lane / 5;         // 0..11 live, 12 = idle (lanes 60-63)
  int fi = lane % 5;          // feature oct (feats 8fi..8fi+7)
  bool active = grp < 12;
  int j0 = rs[node], j1 = rs[node + 1];
  float a0 = 0.f, a1 = 0.f, a2 = 0.f, a3 = 0.f;
  float a4 = 0.f, a5 = 0.f, a6 = 0.f, a7 = 0.f;
  int j = j0;
  for (; j + 24 <= j1; j += 24) {   // 24 edges in flight
    if (active) {
      int2 e0 = epack[j + grp];
      int2 e1 = epack[j + 12 + grp];
      uint4 q0 = gb4[(size_t)e0.x * 5 + fi];
      uint4 q1 = gb4[(size_t)e1.x * 5 + fi];
      float v0 = __int_as_float(e0.y), v1 = __int_as_float(e1.y);
      a0 += v0 * bflo(q0.x); a1 += v0 * bfhi(q0.x);
      a2 += v0 * bflo(q0.y); a3 += v0 * bfhi(q0.y);
      a4 += v0 * bflo(q0.z); a5 += v0 * bfhi(q0.z);
      a6 += v0 * bflo(q0.w); a7 += v0 * bfhi(q0.w);
      a0 += v1 * bflo(q1.x); a1 += v1 * bfhi(q1.x);
      a2 += v1 * bflo(q1.y); a3 += v1 * bfhi(q1.y);
      a4 += v1 * bflo(q1.z); a5 += v1 * bfhi(q1.z);
      a6 += v1 * bflo(q1.w); a7 += v1 * bfhi(q1.w);
    }
  }
  for (; j + 12 <= j1; j += 12) {
    if (active) {
      int2 e = epack[j + grp];
      uint4 q = gb4[(size_t)e.x * 5 + fi];
      float v = __int_as_float(e.y);
      a0 += v * bflo(q.x); a1 += v * bfhi(q.x);
      a2 += v * bflo(q.y); a3 += v * bfhi(q.y);
      a4 += v * bflo(q.z); a5 += v * bfhi(q.z);
      a6 += v * bflo(q.w); a7 += v * bfhi(q.w);
    }
  }
  if (active && grp < j1 - j) {     // tail 0..11 edges
    int2 e = epack[j + grp];
    uint4 q = gb4[(size_t)e.x * 5 + fi];
    float v = __int_as_float(e.y);
    a0 += v * bflo(q.x); a1 += v * bfhi(q.x);
    a2 += v * bflo(q.y); a3 += v * bfhi(q.y);
    a4 += v * bflo(q.z); a5 += v * bfhi(q.z);
    a6 += v * bflo(q.w); a7 += v * bfhi(q.w);
  }
  // merge 12 groups of 5 lanes: +30, +15, then +5 and +10
  float t0, t1, t2, t3, t4, t5, t6, t7;
  t0 = __shfl(a0, lane + 30, 64); t1 = __shfl(a1, lane + 30, 64);
  t2 = __shfl(a2, lane + 30, 64); t3 = __shfl(a3, lane + 30, 64);
  t4 = __shfl(a4, lane + 30, 64); t5 = __shfl(a5, lane + 30, 64);
  t6 = __shfl(a6, lane + 30, 64); t7 = __shfl(a7, lane + 30, 64);
  if (lane < 30) { a0 += t0; a1 += t1; a2 += t2; a3 += t3;
                   a4 += t4; a5 += t5; a6 += t6; a7 += t7; }
  t0 = __shfl(a0, lane + 15, 64); t1 = __shfl(a1, lane + 15, 64);
  t2 = __shfl(a2, lane + 15, 64); t3 = __shfl(a3, lane + 15, 64);
  t4 = __shfl(a4, lane + 15, 64); t5 = __shfl(a5, lane + 15, 64);
  t6 = __shfl(a6, lane + 15, 64); t7 = __shfl(a7, lane + 15, 64);
  if (lane < 15) { a0 += t0; a1 += t1; a2 += t2; a3 += t3;
                   a4 += t4; a5 += t5; a6 += t6; a7 += t7; }
  float u0, u1, u2, u3, u4, u5, u6, u7;
  t0 = __shfl(a0, lane + 5, 64);  t1 = __shfl(a1, lane + 5, 64);
  t2 = __shfl(a2, lane + 5, 64);  t3 = __shfl(a3, lane + 5, 64);
  t4 = __shfl(a4, lane + 5, 64);  t5 = __shfl(a5, lane + 5, 64);
  t6 = __shfl(a6, lane + 5, 64);  t7 = __shfl(a7, lane + 5, 64);
  u0 = __shfl(a0, lane + 10, 64); u1 = __shfl(a1, lane + 10, 64);
  u2 = __shfl(a2, lane + 10, 64); u3 = __shfl(a3, lane + 10, 64);
  u4 = __shfl(a4, lane + 10, 64); u5 = __shfl(a5, lane + 10, 64);
  u6 = __shfl(a6, lane + 10, 64); u7 = __shfl(a7, lane + 10, 64);
  if (lane < 5) {
    a0 += t0 + u0; a1 += t1 + u1; a2 += t2 + u2; a3 += t3 + u3;
    a4 += t4 + u4; a5 += t5 + u5; a6 += t6 + u6; a7 += t7 + u7;
    float4 o0; o0.x = a0; o0.y = a1; o0.z = a2; o0.w = a3;
    float4 o1; o1.x = a4; o1.y = a5; o1.z = a6; o1.w = a7;
    *(float4*)&out[(size_t)node * F_OUT + fi * 8] = o0;
    *(float4*)&out[(size_t)node * F_OUT + fi * 8 + 4] = o1;
  }
}

extern "C" void kernel_launch(void* const* d_in, const int* in_sizes, int n_in,
                              void* d_out, int out_size, void* d_ws, size_t ws_size,
                              hipStream_t stream) {
  const int* src = (const int*)d_in[0];
  const int* dst = (const int*)d_in[1];
  const float* vals = (const float*)d_in[2];
  const float* x = (const float*)d_in[3];
  const float* W1 = (const float*)d_in[4];
  const float* W2 = (const float*)d_in[5];
  float* out = (float*)d_out;

  // 16B-aligned workspace layout (~37.9 MB)
  int* rs = (int*)d_ws;                            // 80001 used, pad to 80004
  int* counts = rs + 80004;                        // 320*313 = 100160 ints
  int* btot = counts + 100160;                     // 313, pad to 320
  int* bbase = btot + 320;                         // 314, pad to 320
  int2* epack = (int2*)(bbase + 320);              // byte off 723216 (16B-aligned)
  unsigned short* xb = (unsigned short*)(epack + N_EDGES);   // 5.12M bf16
  unsigned short* gb = xb + (size_t)N_NODES * F_IN;          // 3.2M bf16
  unsigned short* sxgb = gb + (size_t)N_NODES * F_OUT;       // 5.12M bf16 (also estg)
  unsigned short* w1p = sxgb + (size_t)N_NODES * F_IN;       // 8192 bf16
  unsigned short* w2p = w1p + 8192;                          // 6144 bf16
  int2* estg = (int2*)sxgb;   // staging aliases sxgb (dead until gather1)

  xcvt_kernel<<<(N_NODES * F_IN / 4 + 255) / 256, 256, 0, stream>>>(
      (const float4*)x, (ushort4*)xb);
  wpack_kernel<<<(8192 + 6144 + 255) / 256, 256, 0, stream>>>(W1, W2, w1p, w2p);
  histB_kernel<<<B1, 256, 0, stream>>>(src, counts);
  scan2_kernel<<<NB, 320, 0, stream>>>(counts, btot);
  scanT_kernel<<<1, 320, 0, stream>>>(btot, bbase, rs);
  place_kernel<<<B1, 256, 0, stream>>>(src, dst, vals, counts, bbase, estg);
  permute_kernel<<<NB, 512, 0, stream>>>(bbase, estg, epack, rs);
  gather1_kernel<<<(N_NODES * 64 + 255) / 256, 256, 0, stream>>>(
      rs, epack, (const uint4*)xb, (uint4*)sxgb);
  dense_kernel<<<N_NODES / 32, 256, 0, stream>>>(
      (const uint4*)sxgb, (const uint4*)w1p, (const uint4*)w2p, gb);
  spmm2_kernel<<<(N_NODES * 64 + 255) / 256, 256, 0, stream>>>(
      rs, epack, (const uint4*)gb, out);
}